// Round 3
// baseline (4333.712 us; speedup 1.0000x reference)
//
#include <hip/hip_runtime.h>
#include <hip/hip_bf16.h>

typedef __hip_bfloat16 bf16;
typedef __attribute__((ext_vector_type(8))) short short8;
typedef __attribute__((ext_vector_type(4))) short s16x4;
typedef __attribute__((ext_vector_type(4))) float f32x4;

#define TB 128      // batch
#define TT 128      // time
#define EMB 512     // embed dim
#define HH 512      // per-direction hidden
#define G4 2048     // 4*HH gate dim
#define NROWS 512   // 4 runs * 128 batch
#define F4 4096     // feature dim
#define HD 1024     // mlp hidden

__device__ __forceinline__ bf16 f2bf(float x){ return __float2bfloat16(x); }
__device__ __forceinline__ float bf2f(bf16 x){ return __bfloat162float(x); }

// ---------------------------------------------------------------------------
// f32 -> bf16 conversion (grid-stride, float4 granularity)
// ---------------------------------------------------------------------------
__global__ __launch_bounds__(256) void k_cvt(const float* __restrict__ src,
                                             bf16* __restrict__ dst, int n4)
{
    for (int i = blockIdx.x * 256 + threadIdx.x; i < n4; i += gridDim.x * 256) {
        float4 v = reinterpret_cast<const float4*>(src)[i];
        s16x4 o;
        o[0] = (short)__bfloat16_as_ushort(f2bf(v.x));
        o[1] = (short)__bfloat16_as_ushort(f2bf(v.y));
        o[2] = (short)__bfloat16_as_ushort(f2bf(v.z));
        o[3] = (short)__bfloat16_as_ushort(f2bf(v.w));
        reinterpret_cast<s16x4*>(dst)[i] = o;
    }
}

// ---------------------------------------------------------------------------
// Gather embed rows to bf16 x_bf[s][t][b][e]  (ws-size permitting)
// ---------------------------------------------------------------------------
__global__ __launch_bounds__(256) void k_gather(
    const int* __restrict__ tok_h, const int* __restrict__ tok_p,
    const float* __restrict__ embed, bf16* __restrict__ x_bf)
{
    const int total4 = 2 * TT * TB * (EMB / 4);
    for (int g = blockIdx.x * 256 + threadIdx.x; g < total4; g += gridDim.x * 256) {
        int e4 = g & (EMB / 4 - 1);
        int b  = (g >> 7) & 127;
        int t  = (g >> 14) & 127;
        int s  = g >> 21;
        int tok = (s ? tok_p : tok_h)[b * TT + t];
        float4 v = reinterpret_cast<const float4*>(embed + (size_t)tok * EMB)[e4];
        s16x4 o;
        o[0] = (short)__bfloat16_as_ushort(f2bf(v.x));
        o[1] = (short)__bfloat16_as_ushort(f2bf(v.y));
        o[2] = (short)__bfloat16_as_ushort(f2bf(v.z));
        o[3] = (short)__bfloat16_as_ushort(f2bf(v.w));
        reinterpret_cast<s16x4*>(x_bf + (((size_t)s * TT + t) * TB + b) * EMB)[e4] = o;
    }
}

// ---------------------------------------------------------------------------
// One LSTM step for all 512 rows (4 runs x 128 batch), x-projection fused.
// grid = 256 blocks: mi = bx>>5 (64-row slice), ji = bx&31 (16 h-cols)
// wave w computes gate-w preactivations [64r x 16c] =
//      x_t @ W_ih^T + (h_hi + h_lo) @ W_hh^T
// h kept as bf16 hi/lo pair (~f32 recurrent precision). c stays f32 in ws.
// Each block's 64 rows lie in ONE run (mi>>1) -> uniform direction/sentence.
// ---------------------------------------------------------------------------
template<int GATH>
__global__ __launch_bounds__(256) void k_step(
    const bf16* __restrict__ x_bf, const float* __restrict__ embed,
    const int* __restrict__ tok_h, const int* __restrict__ tok_p,
    const bf16* __restrict__ W_ihb, const bf16* __restrict__ W_hhb,
    const float* __restrict__ b_ih, const float* __restrict__ b_hh,
    const bf16* __restrict__ h_hi_in, const bf16* __restrict__ h_lo_in,
    bf16* __restrict__ h_hi_out, bf16* __restrict__ h_lo_out,
    float* __restrict__ c_buf, float* __restrict__ h_fin, int t)
{
    __shared__ float lds[4][64][17];

    const int blk = blockIdx.x;
    const int mi = blk >> 5;          // 0..7  (64-row slice)
    const int ji = blk & 31;          // 0..31 (16-col slice)
    const int w    = threadIdx.x >> 6;
    const int lane = threadIdx.x & 63;
    const int l16 = lane & 15;
    const int kq  = lane >> 4;

    const int run = mi >> 1;          // 0 hypF, 1 hypB, 2 premF, 3 premB
    const int s   = run >> 1;
    const int te  = (run & 1) ? (TT - 1 - t) : t;
    const int r0  = mi * 64;

    // per-lane A-row pointers (4 mtiles)
    const bf16*  hhp[4];
    const bf16*  hlp[4];
    const bf16*  xbp[4];
    const float* xfp[4];
#pragma unroll
    for (int mt = 0; mt < 4; ++mt) {
        int r = r0 + mt * 16 + l16;
        hhp[mt] = h_hi_in + (size_t)r * HH;
        hlp[mt] = h_lo_in + (size_t)r * HH;
        int b = r & 127;
        if (GATH) {
            xbp[mt] = x_bf + (((size_t)s * TT + te) * TB + b) * EMB;
        } else {
            int tok = (s ? tok_p : tok_h)[b * TT + te];
            xfp[mt] = embed + (size_t)tok * EMB;
        }
    }

    const int gcol = w * HH + ji * 16 + l16;
    const bf16* wh = W_hhb + (size_t)gcol * HH;
    const bf16* wx = W_ihb + (size_t)gcol * EMB;

    f32x4 acc[4];
#pragma unroll
    for (int mt = 0; mt < 4; ++mt) acc[mt] = (f32x4)0.f;

    for (int kk = 0; kk < HH / 32; ++kk) {
        const int k0 = kk * 32 + kq * 8;
        short8 bwh = *reinterpret_cast<const short8*>(wh + k0);
        short8 bwx = *reinterpret_cast<const short8*>(wx + k0);
#pragma unroll
        for (int mt = 0; mt < 4; ++mt) {
            short8 ax;
            if (GATH) {
                ax = *reinterpret_cast<const short8*>(xbp[mt] + k0);
            } else {
                float4 v0 = *reinterpret_cast<const float4*>(xfp[mt] + k0);
                float4 v1 = *reinterpret_cast<const float4*>(xfp[mt] + k0 + 4);
                ax[0] = (short)__bfloat16_as_ushort(f2bf(v0.x));
                ax[1] = (short)__bfloat16_as_ushort(f2bf(v0.y));
                ax[2] = (short)__bfloat16_as_ushort(f2bf(v0.z));
                ax[3] = (short)__bfloat16_as_ushort(f2bf(v0.w));
                ax[4] = (short)__bfloat16_as_ushort(f2bf(v1.x));
                ax[5] = (short)__bfloat16_as_ushort(f2bf(v1.y));
                ax[6] = (short)__bfloat16_as_ushort(f2bf(v1.z));
                ax[7] = (short)__bfloat16_as_ushort(f2bf(v1.w));
            }
            short8 ahi = *reinterpret_cast<const short8*>(hhp[mt] + k0);
            short8 alo = *reinterpret_cast<const short8*>(hlp[mt] + k0);
            acc[mt] = __builtin_amdgcn_mfma_f32_16x16x32_bf16(ax,  bwx, acc[mt], 0, 0, 0);
            acc[mt] = __builtin_amdgcn_mfma_f32_16x16x32_bf16(alo, bwh, acc[mt], 0, 0, 0);
            acc[mt] = __builtin_amdgcn_mfma_f32_16x16x32_bf16(ahi, bwh, acc[mt], 0, 0, 0);
        }
    }
#pragma unroll
    for (int mt = 0; mt < 4; ++mt)
#pragma unroll
        for (int q = 0; q < 4; ++q)
            lds[w][mt * 16 + kq * 4 + q][l16] = acc[mt][q];
    __syncthreads();

    // ---- phase 2: elementwise LSTM cell update, 4 cells per thread ----
    const int tid = threadIdx.x;
#pragma unroll
    for (int q = 0; q < 4; ++q) {
        int cell = tid + q * 256;      // 0..1023 = 64 rows x 16 cols
        int rl  = cell >> 4;
        int col = cell & 15;
        int r = r0 + rl;
        int j = ji * 16 + col;

        float pi = lds[0][rl][col] + b_ih[j]          + b_hh[j];
        float pf = lds[1][rl][col] + b_ih[HH + j]     + b_hh[HH + j];
        float pg = lds[2][rl][col] + b_ih[2 * HH + j] + b_hh[2 * HH + j];
        float po = lds[3][rl][col] + b_ih[3 * HH + j] + b_hh[3 * HH + j];

        float si = 1.f / (1.f + expf(-pi));
        float sf = 1.f / (1.f + expf(-pf));
        float so = 1.f / (1.f + expf(-po));
        float tg = tanhf(pg);

        size_t idx = (size_t)r * HH + j;
        float cn = sf * c_buf[idx] + si * tg;
        float hn = so * tanhf(cn);
        c_buf[idx] = cn;

        bf16 hi = f2bf(hn);
        h_hi_out[idx] = hi;
        h_lo_out[idx] = f2bf(hn - bf2f(hi));
        if (t == TT - 1) h_fin[idx] = hn;
    }
}

// ---------------------------------------------------------------------------
// features [hyp, prem, prem-hyp, hyp*prem] + LayerNorm(4096); block per row
// ---------------------------------------------------------------------------
__global__ __launch_bounds__(256) void k_feat_ln0(
    const float* __restrict__ h_fin, const float* __restrict__ g,
    const float* __restrict__ be, bf16* __restrict__ f_out)
{
    const int b = blockIdx.x;
    const int tid = threadIdx.x;
    float v[16];
    float s = 0.f, sq = 0.f;
#pragma unroll
    for (int i = 0; i < 16; ++i) {
        int e = i * 256 + tid;
        int region = e >> 10;
        int idx = e & 1023;
        int runh = (idx < 512) ? 0 : 1;
        int jj = idx & 511;
        float hy = h_fin[((size_t)(runh * TB + b)) * HH + jj];
        float pr = h_fin[((size_t)((runh + 2) * TB + b)) * HH + jj];
        float val = (region == 0) ? hy : (region == 1) ? pr
                  : (region == 2) ? (pr - hy) : (hy * pr);
        v[i] = val;
        s += val;
        sq += val * val;
    }
    __shared__ float shs[4], shq[4];
    for (int o = 32; o; o >>= 1) { s += __shfl_down(s, o); sq += __shfl_down(sq, o); }
    int w = tid >> 6, lane = tid & 63;
    if (!lane) { shs[w] = s; shq[w] = sq; }
    __syncthreads();
    s  = shs[0] + shs[1] + shs[2] + shs[3];
    sq = shq[0] + shq[1] + shq[2] + shq[3];
    float mean = s / (float)F4;
    float var  = sq / (float)F4 - mean * mean;
    float rstd = rsqrtf(var + 1e-6f);
#pragma unroll
    for (int i = 0; i < 16; ++i) {
        int e = i * 256 + tid;
        float nv = (v[i] - mean) * rstd * g[e] + be[e];
        f_out[(size_t)b * F4 + e] = f2bf(nv);
    }
}

// ---------------------------------------------------------------------------
// MLP layer  C[128,1024] = relu(A[128,K] @ Bw[1024,K]^T + bias), f32 out
// ---------------------------------------------------------------------------
template<int K>
__global__ __launch_bounds__(256) void k_mlp(
    const bf16* __restrict__ A, const bf16* __restrict__ Bw,
    const float* __restrict__ bias, float* __restrict__ C)
{
    const int nb = blockIdx.x;   // 0..15
    const int mb = blockIdx.y;   // 0..1
    const int w    = threadIdx.x >> 6;
    const int lane = threadIdx.x & 63;
    const int wr = w >> 1, wc = w & 1;
    const int l16 = lane & 15;
    const int kq  = lane >> 4;
    const int m0 = mb * 64 + wr * 32;
    const int c0 = nb * 64 + wc * 32;

    f32x4 acc[2][2];
#pragma unroll
    for (int i = 0; i < 2; ++i)
#pragma unroll
        for (int j = 0; j < 2; ++j) acc[i][j] = (f32x4)0.f;

    for (int kk = 0; kk < K / 32; ++kk) {
        const int k0 = kk * 32 + kq * 8;
        short8 a[2], bb[2];
#pragma unroll
        for (int i = 0; i < 2; ++i)
            a[i] = *reinterpret_cast<const short8*>(A + (size_t)(m0 + i * 16 + l16) * K + k0);
#pragma unroll
        for (int j = 0; j < 2; ++j)
            bb[j] = *reinterpret_cast<const short8*>(Bw + (size_t)(c0 + j * 16 + l16) * K + k0);
#pragma unroll
        for (int i = 0; i < 2; ++i)
#pragma unroll
            for (int j = 0; j < 2; ++j)
                acc[i][j] = __builtin_amdgcn_mfma_f32_16x16x32_bf16(a[i], bb[j], acc[i][j], 0, 0, 0);
    }
#pragma unroll
    for (int i = 0; i < 2; ++i)
#pragma unroll
        for (int j = 0; j < 2; ++j) {
            int gg = c0 + j * 16 + l16;
            float bv = bias[gg];
#pragma unroll
            for (int q = 0; q < 4; ++q) {
                int m = m0 + i * 16 + kq * 4 + q;
                C[(size_t)m * HD + gg] = fmaxf(acc[i][j][q] + bv, 0.f);
            }
        }
}

// ---------------------------------------------------------------------------
// LayerNorm over 1024 (f32 in, bf16 out), one block per row
// ---------------------------------------------------------------------------
__global__ __launch_bounds__(256) void k_ln(
    const float* __restrict__ x, const float* __restrict__ g,
    const float* __restrict__ be, bf16* __restrict__ out)
{
    const int b = blockIdx.x;
    const int tid = threadIdx.x;
    float v[4];
    float s = 0.f, sq = 0.f;
#pragma unroll
    for (int i = 0; i < 4; ++i) {
        int e = i * 256 + tid;
        float val = x[(size_t)b * HD + e];
        v[i] = val; s += val; sq += val * val;
    }
    __shared__ float shs[4], shq[4];
    for (int o = 32; o; o >>= 1) { s += __shfl_down(s, o); sq += __shfl_down(sq, o); }
    int w = tid >> 6, lane = tid & 63;
    if (!lane) { shs[w] = s; shq[w] = sq; }
    __syncthreads();
    s  = shs[0] + shs[1] + shs[2] + shs[3];
    sq = shq[0] + shq[1] + shq[2] + shq[3];
    float mean = s / (float)HD;
    float var  = sq / (float)HD - mean * mean;
    float rstd = rsqrtf(var + 1e-6f);
#pragma unroll
    for (int i = 0; i < 4; ++i) {
        int e = i * 256 + tid;
        float nv = (v[i] - mean) * rstd * g[e] + be[e];
        out[(size_t)b * HD + e] = f2bf(nv);
    }
}

// ---------------------------------------------------------------------------
// output projection [128,3] = x[128,1024] @ out_W[3,1024]^T + b  (f32 out)
// ---------------------------------------------------------------------------
__global__ __launch_bounds__(256) void k_out(
    const bf16* __restrict__ x, const float* __restrict__ Wt,
    const float* __restrict__ bias, float* __restrict__ out)
{
    const int b = blockIdx.x;
    const int tid = threadIdx.x;
    float p0 = 0.f, p1 = 0.f, p2 = 0.f;
    for (int k = tid; k < HD; k += 256) {
        float xv = bf2f(x[(size_t)b * HD + k]);
        p0 += xv * Wt[k];
        p1 += xv * Wt[HD + k];
        p2 += xv * Wt[2 * HD + k];
    }
    for (int o = 32; o; o >>= 1) {
        p0 += __shfl_down(p0, o);
        p1 += __shfl_down(p1, o);
        p2 += __shfl_down(p2, o);
    }
    __shared__ float sh[4][3];
    int w = tid >> 6, lane = tid & 63;
    if (!lane) { sh[w][0] = p0; sh[w][1] = p1; sh[w][2] = p2; }
    __syncthreads();
    if (tid < 3) {
        out[b * 3 + tid] = sh[0][tid] + sh[1][tid] + sh[2][tid] + sh[3][tid] + bias[tid];
    }
}

// ---------------------------------------------------------------------------
extern "C" void kernel_launch(void* const* d_in, const int* in_sizes, int n_in,
                              void* d_out, int out_size, void* d_ws, size_t ws_size,
                              hipStream_t stream)
{
    const int*   tok_h  = (const int*)  d_in[0];
    const int*   tok_p  = (const int*)  d_in[1];
    const float* embed  = (const float*)d_in[2];
    const float* W_ih   = (const float*)d_in[3];
    const float* W_hh   = (const float*)d_in[4];
    const float* b_ih   = (const float*)d_in[5];
    const float* b_hh   = (const float*)d_in[6];
    const float* mlp1_W = (const float*)d_in[7];
    const float* mlp1_b = (const float*)d_in[8];
    const float* mlp2_W = (const float*)d_in[9];
    const float* mlp2_b = (const float*)d_in[10];
    const float* out_W  = (const float*)d_in[11];
    const float* out_b  = (const float*)d_in[12];
    const float* ln0_g  = (const float*)d_in[13];
    const float* ln0_b  = (const float*)d_in[14];
    const float* ln1_g  = (const float*)d_in[15];
    const float* ln1_b  = (const float*)d_in[16];
    const float* ln2_g  = (const float*)d_in[17];
    const float* ln2_b  = (const float*)d_in[18];

    char* ws = (char*)d_ws;
    size_t off = 0;
    bf16*  W_ihb = (bf16*)(ws + off); off += (size_t)G4 * EMB * 2;          // 2 MB
    bf16*  W_hhb = (bf16*)(ws + off); off += (size_t)G4 * HH * 2;           // 2 MB
    bf16*  mlp1b = (bf16*)(ws + off); off += (size_t)HD * F4 * 2;           // 8 MB
    bf16*  mlp2b = (bf16*)(ws + off); off += (size_t)HD * HD * 2;           // 2 MB
    bf16*  h_hi  = (bf16*)(ws + off); off += (size_t)2 * NROWS * HH * 2;    // 1 MB
    bf16*  h_lo  = (bf16*)(ws + off); off += (size_t)2 * NROWS * HH * 2;    // 1 MB
    float* c_buf = (float*)(ws + off); off += (size_t)NROWS * HH * 4;       // 1 MB
    float* h_fin = (float*)(ws + off); off += (size_t)NROWS * HH * 4;       // 1 MB
    bf16*  f_ln0 = (bf16*)(ws + off); off += (size_t)TB * F4 * 2;
    float* act1  = (float*)(ws + off); off += (size_t)TB * HD * 4;
    bf16*  f_ln1 = (bf16*)(ws + off); off += (size_t)TB * HD * 2;
    float* act2  = (float*)(ws + off); off += (size_t)TB * HD * 4;
    bf16*  f_ln2 = (bf16*)(ws + off); off += (size_t)TB * HD * 2;
    size_t x_need = (size_t)2 * TT * TB * EMB * 2;                          // 32 MB
    bool use_gather = (ws_size >= off + x_need + (1 << 20));
    bf16*  x_bf  = (bf16*)(ws + off);

    // zero h (both parities, hi+lo) and c — contiguous region
    size_t HB = (size_t)2 * NROWS * HH * sizeof(bf16);
    (void)hipMemsetAsync(h_hi, 0, 2 * HB + (size_t)NROWS * HH * 4, stream);

    // weight f32 -> bf16 conversion
    k_cvt<<<512, 256, 0, stream>>>(W_ih,   W_ihb, G4 * EMB / 4);
    k_cvt<<<512, 256, 0, stream>>>(W_hh,   W_hhb, G4 * HH / 4);
    k_cvt<<<512, 256, 0, stream>>>(mlp1_W, mlp1b, HD * F4 / 4);
    k_cvt<<<512, 256, 0, stream>>>(mlp2_W, mlp2b, HD * HD / 4);

    if (use_gather)
        k_gather<<<4096, 256, 0, stream>>>(tok_h, tok_p, embed, x_bf);

    // LSTM recurrence: 128 steps, 4 runs batched as 512 rows
    const size_t HS = (size_t)NROWS * HH;
    for (int t = 0; t < TT; ++t) {
        int p = t & 1;
        if (use_gather)
            k_step<1><<<256, 256, 0, stream>>>(x_bf, embed, tok_h, tok_p,
                W_ihb, W_hhb, b_ih, b_hh,
                h_hi + (size_t)p * HS, h_lo + (size_t)p * HS,
                h_hi + (size_t)(p ^ 1) * HS, h_lo + (size_t)(p ^ 1) * HS,
                c_buf, h_fin, t);
        else
            k_step<0><<<256, 256, 0, stream>>>(x_bf, embed, tok_h, tok_p,
                W_ihb, W_hhb, b_ih, b_hh,
                h_hi + (size_t)p * HS, h_lo + (size_t)p * HS,
                h_hi + (size_t)(p ^ 1) * HS, h_lo + (size_t)(p ^ 1) * HS,
                c_buf, h_fin, t);
    }

    // head
    k_feat_ln0<<<TB, 256, 0, stream>>>(h_fin, ln0_g, ln0_b, f_ln0);
    k_mlp<F4><<<dim3(16, 2), 256, 0, stream>>>(f_ln0, mlp1b, mlp1_b, act1);
    k_ln<<<TB, 256, 0, stream>>>(act1, ln1_g, ln1_b, f_ln1);
    k_mlp<HD><<<dim3(16, 2), 256, 0, stream>>>(f_ln1, mlp2b, mlp2_b, act2);
    k_ln<<<TB, 256, 0, stream>>>(act2, ln2_g, ln2_b, f_ln2);
    k_out<<<TB, 256, 0, stream>>>(f_ln2, out_W, out_b, (float*)d_out);
}

// Round 4
// 4015.170 us; speedup vs baseline: 1.0793x; 1.0793x over previous
//
#include <hip/hip_runtime.h>
#include <hip/hip_bf16.h>

typedef __hip_bfloat16 bf16;
typedef __attribute__((ext_vector_type(8))) short short8;
typedef __attribute__((ext_vector_type(4))) short s16x4;
typedef __attribute__((ext_vector_type(4))) float f32x4;

#define TB 128      // batch
#define TT 128      // time
#define EMB 512     // embed dim
#define HH 512      // per-direction hidden
#define G4 2048     // 4*HH gate dim
#define NROWS 512   // 4 runs * 128 batch
#define F4 4096     // feature dim
#define HD 1024     // mlp hidden

__device__ __forceinline__ bf16 f2bf(float x){ return __float2bfloat16(x); }
__device__ __forceinline__ float bf2f(bf16 x){ return __bfloat162float(x); }

__device__ __forceinline__ short8 pack8(float4 a, float4 b){
    short8 r;
    r[0] = (short)__bfloat16_as_ushort(f2bf(a.x));
    r[1] = (short)__bfloat16_as_ushort(f2bf(a.y));
    r[2] = (short)__bfloat16_as_ushort(f2bf(a.z));
    r[3] = (short)__bfloat16_as_ushort(f2bf(a.w));
    r[4] = (short)__bfloat16_as_ushort(f2bf(b.x));
    r[5] = (short)__bfloat16_as_ushort(f2bf(b.y));
    r[6] = (short)__bfloat16_as_ushort(f2bf(b.z));
    r[7] = (short)__bfloat16_as_ushort(f2bf(b.w));
    return r;
}

// ---------------------------------------------------------------------------
// f32 -> bf16 conversion (fallback path only: W_ih/W_hh)
// ---------------------------------------------------------------------------
__global__ __launch_bounds__(256) void k_cvt(const float* __restrict__ src,
                                             bf16* __restrict__ dst, int n4)
{
    for (int i = blockIdx.x * 256 + threadIdx.x; i < n4; i += gridDim.x * 256) {
        float4 v = reinterpret_cast<const float4*>(src)[i];
        s16x4 o;
        o[0] = (short)__bfloat16_as_ushort(f2bf(v.x));
        o[1] = (short)__bfloat16_as_ushort(f2bf(v.y));
        o[2] = (short)__bfloat16_as_ushort(f2bf(v.z));
        o[3] = (short)__bfloat16_as_ushort(f2bf(v.w));
        reinterpret_cast<s16x4*>(dst)[i] = o;
    }
}

// ---------------------------------------------------------------------------
// Gather embed rows to bf16 x_bf[s][t][b][e]
// ---------------------------------------------------------------------------
__global__ __launch_bounds__(256) void k_gather(
    const int* __restrict__ tok_h, const int* __restrict__ tok_p,
    const float* __restrict__ embed, bf16* __restrict__ x_bf)
{
    const int total4 = 2 * TT * TB * (EMB / 4);
    for (int g = blockIdx.x * 256 + threadIdx.x; g < total4; g += gridDim.x * 256) {
        int e4 = g & (EMB / 4 - 1);
        int b  = (g >> 7) & 127;
        int t  = (g >> 14) & 127;
        int s  = g >> 21;
        int tok = (s ? tok_p : tok_h)[b * TT + t];
        float4 v = reinterpret_cast<const float4*>(embed + (size_t)tok * EMB)[e4];
        s16x4 o;
        o[0] = (short)__bfloat16_as_ushort(f2bf(v.x));
        o[1] = (short)__bfloat16_as_ushort(f2bf(v.y));
        o[2] = (short)__bfloat16_as_ushort(f2bf(v.z));
        o[3] = (short)__bfloat16_as_ushort(f2bf(v.w));
        reinterpret_cast<s16x4*>(x_bf + (((size_t)s * TT + t) * TB + b) * EMB)[e4] = o;
    }
}

// ---------------------------------------------------------------------------
// PERSISTENT LSTM: one launch, 128 steps, barrier per step within mi-groups.
// 256 blocks: mi = bx&7 (64-row slice, co-XCD under round-robin), cj = bx>>3
// (16 h-cols). Block computes all 4 gates for its 64 rows x 16 h-cols.
// W_ih + W_hh slices staged once in LDS (bf16, slot-XOR swizzle).
// h = bf16 hi/lo pair in global (parity double-buffer); c in registers.
// ---------------------------------------------------------------------------
__global__ __launch_bounds__(256) void k_persist(
    const bf16* __restrict__ x_bf,
    const float* __restrict__ W_ih, const float* __restrict__ W_hh,
    const float* __restrict__ b_ih, const float* __restrict__ b_hh,
    bf16* __restrict__ h_hi, bf16* __restrict__ h_lo,
    float* __restrict__ h_fin, int* slots)
{
    __shared__ short Wl[4 * 16 * 16 * 64];   // 128 KB: [g][kk][col][8 slots x 8]
    __shared__ float ga[4][64][17];          // 17.4 KB gate exchange

    const int tid = threadIdx.x;
    const int bx  = blockIdx.x;
    const int mi  = bx & 7;
    const int cj  = bx >> 3;                 // 0..31
    const int w    = tid >> 6;
    const int lane = tid & 63;
    const int l16 = lane & 15;
    const int kq  = lane >> 4;
    const int j0  = cj * 16;
    const int r0  = mi * 64;
    const int run = mi >> 1;                 // 0 hypF, 1 hypB, 2 premF, 3 premB
    const int s   = run >> 1;
    const int dirb = run & 1;

    // ---- prologue: stage W slices into LDS (f32 read, bf16 pack) ----
    {
        int gc  = tid >> 2;                  // 0..63 gate-col index
        int g   = gc >> 4, c = gc & 15;
        int kq4 = tid & 3;
        const float* wxr = W_ih + (size_t)(g * HH + j0 + c) * EMB;
        const float* whr = W_hh + (size_t)(g * HH + j0 + c) * HH;
        for (int kb = 0; kb < 16; ++kb) {
            int k  = kq4 * 128 + kb * 8;
            int kk = k >> 5;
            int eq = (k >> 3) & 3;           // kq-slot within the 32-k tile
            float4 x0 = *(const float4*)(wxr + k);
            float4 x1 = *(const float4*)(wxr + k + 4);
            float4 h0 = *(const float4*)(whr + k);
            float4 h1 = *(const float4*)(whr + k + 4);
            int base = ((g * 16 + kk) * 16 + c) * 64;
            int sx = eq ^ (c & 7);           // Wx slots 0-3 (XOR-swizzled)
            int sh = (eq + 4) ^ (c & 7);     // Wh slots 4-7
            *(short8*)&Wl[base + sx * 8] = pack8(x0, x1);
            *(short8*)&Wl[base + sh * 8] = pack8(h0, h1);
        }
    }

    // per-thread cell constants: all 4 q-cells share column j
    float bsum[4];
    {
        int j = j0 + (tid & 15);
#pragma unroll
        for (int g = 0; g < 4; ++g) bsum[g] = b_ih[g * HH + j] + b_hh[g * HH + j];
    }
    float creg[4] = {0.f, 0.f, 0.f, 0.f};
    __syncthreads();

    const size_t HS = (size_t)NROWS * HH;
    for (int t = 0; t < TT; ++t) {
        const int p  = t & 1;
        const int te = dirb ? (TT - 1 - t) : t;
        const bf16* hb = h_hi + (size_t)p * HS;
        const bf16* lb = h_lo + (size_t)p * HS;
        const bf16* xr0 = x_bf + ((size_t)(s * TT + te) * TB) * EMB;

        f32x4 acc[4];
#pragma unroll
        for (int mt = 0; mt < 4; ++mt) acc[mt] = (f32x4)0.f;

        const bf16 *ph[4], *pl[4], *px[4];
#pragma unroll
        for (int mt = 0; mt < 4; ++mt) {
            int r = r0 + mt * 16 + l16;
            ph[mt] = hb + (size_t)r * HH;
            pl[mt] = lb + (size_t)r * HH;
            px[mt] = xr0 + (size_t)(r & 127) * EMB;
        }

        for (int kk = 0; kk < 16; ++kk) {
            int cb = ((w * 16 + kk) * 16 + l16) * 64;
            short8 fx = *(const short8*)&Wl[cb + ((kq ^ (lane & 7)) * 8)];
            short8 fh = *(const short8*)&Wl[cb + (((kq + 4) ^ (lane & 7)) * 8)];
            int k0 = kk * 32 + kq * 8;
#pragma unroll
            for (int mt = 0; mt < 4; ++mt) {
                short8 ax  = *(const short8*)(px[mt] + k0);
                short8 ahi = *(const short8*)(ph[mt] + k0);
                short8 alo = *(const short8*)(pl[mt] + k0);
                acc[mt] = __builtin_amdgcn_mfma_f32_16x16x32_bf16(ax,  fx, acc[mt], 0, 0, 0);
                acc[mt] = __builtin_amdgcn_mfma_f32_16x16x32_bf16(alo, fh, acc[mt], 0, 0, 0);
                acc[mt] = __builtin_amdgcn_mfma_f32_16x16x32_bf16(ahi, fh, acc[mt], 0, 0, 0);
            }
        }
#pragma unroll
        for (int mt = 0; mt < 4; ++mt)
#pragma unroll
            for (int q = 0; q < 4; ++q)
                ga[w][mt * 16 + kq * 4 + q][l16] = acc[mt][q];
        __syncthreads();

        // ---- phase 2: cell update (4 cells/thread, same column) ----
        bf16* hob = h_hi + (size_t)(p ^ 1) * HS;
        bf16* lob = h_lo + (size_t)(p ^ 1) * HS;
        const int colc = tid & 15;
        const int j = j0 + colc;
#pragma unroll
        for (int q = 0; q < 4; ++q) {
            int rl = (tid >> 4) + q * 16;
            int r  = r0 + rl;
            float pi = ga[0][rl][colc] + bsum[0];
            float pf = ga[1][rl][colc] + bsum[1];
            float pg = ga[2][rl][colc] + bsum[2];
            float po = ga[3][rl][colc] + bsum[3];
            float si = 1.f / (1.f + expf(-pi));
            float sf = 1.f / (1.f + expf(-pf));
            float so = 1.f / (1.f + expf(-po));
            float tg = tanhf(pg);
            float cn = sf * creg[q] + si * tg;
            float hn = so * tanhf(cn);
            creg[q] = cn;
            size_t idx = (size_t)r * HH + j;
            bf16 hi = f2bf(hn);
            hob[idx] = hi;
            lob[idx] = f2bf(hn - bf2f(hi));
            if (t == TT - 1) h_fin[idx] = hn;
        }
        if (t == TT - 1) break;

        // ---- group barrier (32 blocks sharing mi) ----
        __syncthreads();   // drains each wave's stores to L2 (vmcnt before s_barrier)
        if (tid == 0)
            __hip_atomic_store(&slots[mi * 32 + cj], t + 1,
                               __ATOMIC_RELEASE, __HIP_MEMORY_SCOPE_AGENT);
        if (tid < 64) {
            const int tgt = t + 1;
            while (true) {
                int v = (lane < 32)
                    ? __hip_atomic_load(&slots[mi * 32 + lane],
                                        __ATOMIC_RELAXED, __HIP_MEMORY_SCOPE_AGENT)
                    : tgt;
                if (__all(v >= tgt)) break;
                __builtin_amdgcn_s_sleep(1);
            }
            __builtin_amdgcn_fence(__ATOMIC_ACQUIRE, "agent");
        }
        __syncthreads();
    }
}

// ---------------------------------------------------------------------------
// FALLBACK: per-step kernel (round-3, known-good), x fused
// ---------------------------------------------------------------------------
template<int GATH>
__global__ __launch_bounds__(256) void k_step(
    const bf16* __restrict__ x_bf, const float* __restrict__ embed,
    const int* __restrict__ tok_h, const int* __restrict__ tok_p,
    const bf16* __restrict__ W_ihb, const bf16* __restrict__ W_hhb,
    const float* __restrict__ b_ih, const float* __restrict__ b_hh,
    const bf16* __restrict__ h_hi_in, const bf16* __restrict__ h_lo_in,
    bf16* __restrict__ h_hi_out, bf16* __restrict__ h_lo_out,
    float* __restrict__ c_buf, float* __restrict__ h_fin, int t)
{
    __shared__ float lds[4][64][17];

    const int blk = blockIdx.x;
    const int mi = blk >> 5;
    const int ji = blk & 31;
    const int w    = threadIdx.x >> 6;
    const int lane = threadIdx.x & 63;
    const int l16 = lane & 15;
    const int kq  = lane >> 4;

    const int run = mi >> 1;
    const int s   = run >> 1;
    const int te  = (run & 1) ? (TT - 1 - t) : t;
    const int r0  = mi * 64;

    const bf16*  hhp[4];
    const bf16*  hlp[4];
    const bf16*  xbp[4];
    const float* xfp[4];
#pragma unroll
    for (int mt = 0; mt < 4; ++mt) {
        int r = r0 + mt * 16 + l16;
        hhp[mt] = h_hi_in + (size_t)r * HH;
        hlp[mt] = h_lo_in + (size_t)r * HH;
        int b = r & 127;
        if (GATH) {
            xbp[mt] = x_bf + (((size_t)s * TT + te) * TB + b) * EMB;
        } else {
            int tok = (s ? tok_p : tok_h)[b * TT + te];
            xfp[mt] = embed + (size_t)tok * EMB;
        }
    }

    const int gcol = w * HH + ji * 16 + l16;
    const bf16* wh = W_hhb + (size_t)gcol * HH;
    const bf16* wx = W_ihb + (size_t)gcol * EMB;

    f32x4 acc[4];
#pragma unroll
    for (int mt = 0; mt < 4; ++mt) acc[mt] = (f32x4)0.f;

    for (int kk = 0; kk < HH / 32; ++kk) {
        const int k0 = kk * 32 + kq * 8;
        short8 bwh = *reinterpret_cast<const short8*>(wh + k0);
        short8 bwx = *reinterpret_cast<const short8*>(wx + k0);
#pragma unroll
        for (int mt = 0; mt < 4; ++mt) {
            short8 ax;
            if (GATH) {
                ax = *reinterpret_cast<const short8*>(xbp[mt] + k0);
            } else {
                float4 v0 = *reinterpret_cast<const float4*>(xfp[mt] + k0);
                float4 v1 = *reinterpret_cast<const float4*>(xfp[mt] + k0 + 4);
                ax = pack8(v0, v1);
            }
            short8 ahi = *reinterpret_cast<const short8*>(hhp[mt] + k0);
            short8 alo = *reinterpret_cast<const short8*>(hlp[mt] + k0);
            acc[mt] = __builtin_amdgcn_mfma_f32_16x16x32_bf16(ax,  bwx, acc[mt], 0, 0, 0);
            acc[mt] = __builtin_amdgcn_mfma_f32_16x16x32_bf16(alo, bwh, acc[mt], 0, 0, 0);
            acc[mt] = __builtin_amdgcn_mfma_f32_16x16x32_bf16(ahi, bwh, acc[mt], 0, 0, 0);
        }
    }
#pragma unroll
    for (int mt = 0; mt < 4; ++mt)
#pragma unroll
        for (int q = 0; q < 4; ++q)
            lds[w][mt * 16 + kq * 4 + q][l16] = acc[mt][q];
    __syncthreads();

    const int tid = threadIdx.x;
#pragma unroll
    for (int q = 0; q < 4; ++q) {
        int cell = tid + q * 256;
        int rl  = cell >> 4;
        int col = cell & 15;
        int r = r0 + rl;
        int j = ji * 16 + col;

        float pi = lds[0][rl][col] + b_ih[j]          + b_hh[j];
        float pf = lds[1][rl][col] + b_ih[HH + j]     + b_hh[HH + j];
        float pg = lds[2][rl][col] + b_ih[2 * HH + j] + b_hh[2 * HH + j];
        float po = lds[3][rl][col] + b_ih[3 * HH + j] + b_hh[3 * HH + j];

        float si = 1.f / (1.f + expf(-pi));
        float sf = 1.f / (1.f + expf(-pf));
        float so = 1.f / (1.f + expf(-po));
        float tg = tanhf(pg);

        size_t idx = (size_t)r * HH + j;
        float cn = sf * c_buf[idx] + si * tg;
        float hn = so * tanhf(cn);
        c_buf[idx] = cn;

        bf16 hi = f2bf(hn);
        h_hi_out[idx] = hi;
        h_lo_out[idx] = f2bf(hn - bf2f(hi));
        if (t == TT - 1) h_fin[idx] = hn;
    }
}

// ---------------------------------------------------------------------------
// features [hyp, prem, prem-hyp, hyp*prem] + LayerNorm(4096); block per row
// ---------------------------------------------------------------------------
__global__ __launch_bounds__(256) void k_feat_ln0(
    const float* __restrict__ h_fin, const float* __restrict__ g,
    const float* __restrict__ be, bf16* __restrict__ f_out)
{
    const int b = blockIdx.x;
    const int tid = threadIdx.x;
    float v[16];
    float s = 0.f, sq = 0.f;
#pragma unroll
    for (int i = 0; i < 16; ++i) {
        int e = i * 256 + tid;
        int region = e >> 10;
        int idx = e & 1023;
        int runh = (idx < 512) ? 0 : 1;
        int jj = idx & 511;
        float hy = h_fin[((size_t)(runh * TB + b)) * HH + jj];
        float pr = h_fin[((size_t)((runh + 2) * TB + b)) * HH + jj];
        float val = (region == 0) ? hy : (region == 1) ? pr
                  : (region == 2) ? (pr - hy) : (hy * pr);
        v[i] = val;
        s += val;
        sq += val * val;
    }
    __shared__ float shs[4], shq[4];
    for (int o = 32; o; o >>= 1) { s += __shfl_down(s, o); sq += __shfl_down(sq, o); }
    int w = tid >> 6, lane = tid & 63;
    if (!lane) { shs[w] = s; shq[w] = sq; }
    __syncthreads();
    s  = shs[0] + shs[1] + shs[2] + shs[3];
    sq = shq[0] + shq[1] + shq[2] + shq[3];
    float mean = s / (float)F4;
    float var  = sq / (float)F4 - mean * mean;
    float rstd = rsqrtf(var + 1e-6f);
#pragma unroll
    for (int i = 0; i < 16; ++i) {
        int e = i * 256 + tid;
        float nv = (v[i] - mean) * rstd * g[e] + be[e];
        f_out[(size_t)b * F4 + e] = f2bf(nv);
    }
}

// ---------------------------------------------------------------------------
// split-K MLP partial GEMM: part[kc] = A[128,KTOT] @ Bw[1024,KTOT]^T (chunk kc)
// A bf16, Bw f32 (converted in-kernel). grid (16, 2, NCH).
// ---------------------------------------------------------------------------
template<int KTOT, int NCH>
__global__ __launch_bounds__(256) void k_mlp_sk(
    const bf16* __restrict__ A, const float* __restrict__ Bw,
    float* __restrict__ part)
{
    const int KC = KTOT / NCH;
    const int nb = blockIdx.x, mb = blockIdx.y, kc = blockIdx.z;
    const int w    = threadIdx.x >> 6;
    const int lane = threadIdx.x & 63;
    const int wr = w >> 1, wc = w & 1;
    const int l16 = lane & 15;
    const int kq  = lane >> 4;
    const int m0 = mb * 64 + wr * 32;
    const int c0 = nb * 64 + wc * 32;

    f32x4 acc[2][2];
#pragma unroll
    for (int i = 0; i < 2; ++i)
#pragma unroll
        for (int j = 0; j < 2; ++j) acc[i][j] = (f32x4)0.f;

    for (int kk = kc * (KC / 32); kk < (kc + 1) * (KC / 32); ++kk) {
        const int k0 = kk * 32 + kq * 8;
        short8 a[2], bb[2];
#pragma unroll
        for (int i = 0; i < 2; ++i)
            a[i] = *reinterpret_cast<const short8*>(A + (size_t)(m0 + i * 16 + l16) * KTOT + k0);
#pragma unroll
        for (int j = 0; j < 2; ++j) {
            const float* bp = Bw + (size_t)(c0 + j * 16 + l16) * KTOT + k0;
            float4 v0 = *reinterpret_cast<const float4*>(bp);
            float4 v1 = *reinterpret_cast<const float4*>(bp + 4);
            bb[j] = pack8(v0, v1);
        }
#pragma unroll
        for (int i = 0; i < 2; ++i)
#pragma unroll
            for (int j = 0; j < 2; ++j)
                acc[i][j] = __builtin_amdgcn_mfma_f32_16x16x32_bf16(a[i], bb[j], acc[i][j], 0, 0, 0);
    }
#pragma unroll
    for (int i = 0; i < 2; ++i)
#pragma unroll
        for (int j = 0; j < 2; ++j) {
            int gg = c0 + j * 16 + l16;
#pragma unroll
            for (int q = 0; q < 4; ++q) {
                int m = m0 + i * 16 + kq * 4 + q;
                part[((size_t)kc * TB + m) * HD + gg] = acc[i][j][q];
            }
        }
}

// reduce partials + bias + relu -> act (f32)
template<int NCH>
__global__ __launch_bounds__(256) void k_red(
    const float* __restrict__ part, const float* __restrict__ bias,
    float* __restrict__ act)
{
    int i = blockIdx.x * 256 + threadIdx.x;
    if (i < TB * HD) {
        float s = bias[i & (HD - 1)];
#pragma unroll
        for (int c = 0; c < NCH; ++c) s += part[(size_t)c * TB * HD + i];
        act[i] = fmaxf(s, 0.f);
    }
}

// ---------------------------------------------------------------------------
// LayerNorm over 1024 (f32 in, bf16 out)
// ---------------------------------------------------------------------------
__global__ __launch_bounds__(256) void k_ln(
    const float* __restrict__ x, const float* __restrict__ g,
    const float* __restrict__ be, bf16* __restrict__ out)
{
    const int b = blockIdx.x;
    const int tid = threadIdx.x;
    float v[4];
    float s = 0.f, sq = 0.f;
#pragma unroll
    for (int i = 0; i < 4; ++i) {
        int e = i * 256 + tid;
        float val = x[(size_t)b * HD + e];
        v[i] = val; s += val; sq += val * val;
    }
    __shared__ float shs[4], shq[4];
    for (int o = 32; o; o >>= 1) { s += __shfl_down(s, o); sq += __shfl_down(sq, o); }
    int w = tid >> 6, lane = tid & 63;
    if (!lane) { shs[w] = s; shq[w] = sq; }
    __syncthreads();
    s  = shs[0] + shs[1] + shs[2] + shs[3];
    sq = shq[0] + shq[1] + shq[2] + shq[3];
    float mean = s / (float)HD;
    float var  = sq / (float)HD - mean * mean;
    float rstd = rsqrtf(var + 1e-6f);
#pragma unroll
    for (int i = 0; i < 4; ++i) {
        int e = i * 256 + tid;
        float nv = (v[i] - mean) * rstd * g[e] + be[e];
        out[(size_t)b * HD + e] = f2bf(nv);
    }
}

// ---------------------------------------------------------------------------
// output projection [128,3]
// ---------------------------------------------------------------------------
__global__ __launch_bounds__(256) void k_out(
    const bf16* __restrict__ x, const float* __restrict__ Wt,
    const float* __restrict__ bias, float* __restrict__ out)
{
    const int b = blockIdx.x;
    const int tid = threadIdx.x;
    float p0 = 0.f, p1 = 0.f, p2 = 0.f;
    for (int k = tid; k < HD; k += 256) {
        float xv = bf2f(x[(size_t)b * HD + k]);
        p0 += xv * Wt[k];
        p1 += xv * Wt[HD + k];
        p2 += xv * Wt[2 * HD + k];
    }
    for (int o = 32; o; o >>= 1) {
        p0 += __shfl_down(p0, o);
        p1 += __shfl_down(p1, o);
        p2 += __shfl_down(p2, o);
    }
    __shared__ float sh[4][3];
    int w = tid >> 6, lane = tid & 63;
    if (!lane) { sh[w][0] = p0; sh[w][1] = p1; sh[w][2] = p2; }
    __syncthreads();
    if (tid < 3) {
        out[b * 3 + tid] = sh[0][tid] + sh[1][tid] + sh[2][tid] + sh[3][tid] + bias[tid];
    }
}

// ---------------------------------------------------------------------------
extern "C" void kernel_launch(void* const* d_in, const int* in_sizes, int n_in,
                              void* d_out, int out_size, void* d_ws, size_t ws_size,
                              hipStream_t stream)
{
    const int*   tok_h  = (const int*)  d_in[0];
    const int*   tok_p  = (const int*)  d_in[1];
    const float* embed  = (const float*)d_in[2];
    const float* W_ih   = (const float*)d_in[3];
    const float* W_hh   = (const float*)d_in[4];
    const float* b_ih   = (const float*)d_in[5];
    const float* b_hh   = (const float*)d_in[6];
    const float* mlp1_W = (const float*)d_in[7];
    const float* mlp1_b = (const float*)d_in[8];
    const float* mlp2_W = (const float*)d_in[9];
    const float* mlp2_b = (const float*)d_in[10];
    const float* out_W  = (const float*)d_in[11];
    const float* out_b  = (const float*)d_in[12];
    const float* ln0_g  = (const float*)d_in[13];
    const float* ln0_b  = (const float*)d_in[14];
    const float* ln1_g  = (const float*)d_in[15];
    const float* ln1_b  = (const float*)d_in[16];
    const float* ln2_g  = (const float*)d_in[17];
    const float* ln2_b  = (const float*)d_in[18];

    char* ws = (char*)d_ws;
    size_t off = 0;
    bf16*  f_ln0 = (bf16*)(ws + off);  off += (size_t)TB * F4 * 2;            // 1 MB
    float* part  = (float*)(ws + off); off += (size_t)8 * TB * HD * 4;        // 4 MB
    float* act1  = (float*)(ws + off); off += (size_t)TB * HD * 4;
    bf16*  f_ln1 = (bf16*)(ws + off);  off += (size_t)TB * HD * 2;
    float* act2  = (float*)(ws + off); off += (size_t)TB * HD * 4;
    bf16*  f_ln2 = (bf16*)(ws + off);  off += (size_t)TB * HD * 2;
    float* h_fin = (float*)(ws + off); off += (size_t)NROWS * HH * 4;         // 1 MB
    bf16*  h_hi  = (bf16*)(ws + off);  off += (size_t)2 * NROWS * HH * 2;     // 1 MB
    bf16*  h_lo  = (bf16*)(ws + off);  off += (size_t)2 * NROWS * HH * 2;     // 1 MB
    int*   slots = (int*)(ws + off);   off += 4096;
    float* c_buf = (float*)(ws + off); off += (size_t)NROWS * HH * 4;         // 1 MB (fallback)
    bf16*  W_ihb = (bf16*)(ws + off);  off += (size_t)G4 * EMB * 2;           // 2 MB (fallback)
    bf16*  W_hhb = (bf16*)(ws + off);  off += (size_t)G4 * HH * 2;            // 2 MB (fallback)
    size_t off_base = off;
    bf16*  x_bf  = (bf16*)(ws + off);  off += (size_t)2 * TT * TB * EMB * 2;  // 32 MB
    size_t off_full = off;

    const bool have_xbf  = (ws_size >= off_full);
    const bool persist   = have_xbf;   // persistent path needs x_bf only

    // zero h (both parities, hi+lo) + slots (contiguous)
    (void)hipMemsetAsync(h_hi, 0, (size_t)4 * NROWS * HH * 2 + 4096, stream);

    const size_t HS = (size_t)NROWS * HH;
    if (persist) {
        k_gather<<<4096, 256, 0, stream>>>(tok_h, tok_p, embed, x_bf);
        void* args[] = {(void*)&x_bf, (void*)&W_ih, (void*)&W_hh,
                        (void*)&b_ih, (void*)&b_hh,
                        (void*)&h_hi, (void*)&h_lo, (void*)&h_fin, (void*)&slots};
        (void)hipLaunchCooperativeKernel((void*)k_persist, dim3(256), dim3(256),
                                         args, 0, stream);
    } else {
        (void)hipMemsetAsync(c_buf, 0, (size_t)NROWS * HH * 4, stream);
        k_cvt<<<512, 256, 0, stream>>>(W_ih, W_ihb, G4 * EMB / 4);
        k_cvt<<<512, 256, 0, stream>>>(W_hh, W_hhb, G4 * HH / 4);
        for (int t = 0; t < TT; ++t) {
            int p = t & 1;
            k_step<0><<<256, 256, 0, stream>>>(x_bf, embed, tok_h, tok_p,
                W_ihb, W_hhb, b_ih, b_hh,
                h_hi + (size_t)p * HS, h_lo + (size_t)p * HS,
                h_hi + (size_t)(p ^ 1) * HS, h_lo + (size_t)(p ^ 1) * HS,
                c_buf, h_fin, t);
        }
    }
    (void)off_base;

    // head
    k_feat_ln0<<<TB, 256, 0, stream>>>(h_fin, ln0_g, ln0_b, f_ln0);
    k_mlp_sk<F4, 8><<<dim3(16, 2, 8), 256, 0, stream>>>(f_ln0, mlp1_W, part);
    k_red<8><<<512, 256, 0, stream>>>(part, mlp1_b, act1);
    k_ln<<<TB, 256, 0, stream>>>(act1, ln1_g, ln1_b, f_ln1);
    k_mlp_sk<HD, 4><<<dim3(16, 2, 4), 256, 0, stream>>>(f_ln1, mlp2_W, part);
    k_red<4><<<512, 256, 0, stream>>>(part, mlp2_b, act2);
    k_ln<<<TB, 256, 0, stream>>>(act2, ln2_g, ln2_b, f_ln2);
    k_out<<<TB, 256, 0, stream>>>(f_ln2, out_W, out_b, (float*)d_out);
}

// Round 5
// 1118.001 us; speedup vs baseline: 3.8763x; 3.5914x over previous
//
#include <hip/hip_runtime.h>
#include <hip/hip_bf16.h>

typedef __hip_bfloat16 bf16;
typedef __attribute__((ext_vector_type(8))) short short8;
typedef __attribute__((ext_vector_type(4))) short s16x4;
typedef __attribute__((ext_vector_type(4))) float f32x4;

#define TB 128      // batch
#define TT 128      // time
#define EMB 512     // embed dim
#define HH 512      // per-direction hidden
#define G4 2048     // 4*HH gate dim
#define NROWS 512   // 4 runs * 128 batch
#define F4 4096     // feature dim
#define HD 1024     // mlp hidden

__device__ __forceinline__ bf16 f2bf(float x){ return __float2bfloat16(x); }
__device__ __forceinline__ float bf2f(bf16 x){ return __bfloat162float(x); }

__device__ __forceinline__ short8 pack8(float4 a, float4 b){
    short8 r;
    r[0] = (short)__bfloat16_as_ushort(f2bf(a.x));
    r[1] = (short)__bfloat16_as_ushort(f2bf(a.y));
    r[2] = (short)__bfloat16_as_ushort(f2bf(a.z));
    r[3] = (short)__bfloat16_as_ushort(f2bf(a.w));
    r[4] = (short)__bfloat16_as_ushort(f2bf(b.x));
    r[5] = (short)__bfloat16_as_ushort(f2bf(b.y));
    r[6] = (short)__bfloat16_as_ushort(f2bf(b.z));
    r[7] = (short)__bfloat16_as_ushort(f2bf(b.w));
    return r;
}

// ---------------------------------------------------------------------------
// f32 -> bf16 conversion
// ---------------------------------------------------------------------------
__global__ __launch_bounds__(256) void k_cvt(const float* __restrict__ src,
                                             bf16* __restrict__ dst, int n4)
{
    for (int i = blockIdx.x * 256 + threadIdx.x; i < n4; i += gridDim.x * 256) {
        float4 v = reinterpret_cast<const float4*>(src)[i];
        s16x4 o;
        o[0] = (short)__bfloat16_as_ushort(f2bf(v.x));
        o[1] = (short)__bfloat16_as_ushort(f2bf(v.y));
        o[2] = (short)__bfloat16_as_ushort(f2bf(v.z));
        o[3] = (short)__bfloat16_as_ushort(f2bf(v.w));
        reinterpret_cast<s16x4*>(dst)[i] = o;
    }
}

// ---------------------------------------------------------------------------
// Gather embed rows to bf16 x_bf[s][t][b][e]  (fallback paths only)
// ---------------------------------------------------------------------------
__global__ __launch_bounds__(256) void k_gather(
    const int* __restrict__ tok_h, const int* __restrict__ tok_p,
    const float* __restrict__ embed, bf16* __restrict__ x_bf)
{
    const int total4 = 2 * TT * TB * (EMB / 4);
    for (int g = blockIdx.x * 256 + threadIdx.x; g < total4; g += gridDim.x * 256) {
        int e4 = g & (EMB / 4 - 1);
        int b  = (g >> 7) & 127;
        int t  = (g >> 14) & 127;
        int s  = g >> 21;
        int tok = (s ? tok_p : tok_h)[b * TT + t];
        float4 v = reinterpret_cast<const float4*>(embed + (size_t)tok * EMB)[e4];
        s16x4 o;
        o[0] = (short)__bfloat16_as_ushort(f2bf(v.x));
        o[1] = (short)__bfloat16_as_ushort(f2bf(v.y));
        o[2] = (short)__bfloat16_as_ushort(f2bf(v.z));
        o[3] = (short)__bfloat16_as_ushort(f2bf(v.w));
        reinterpret_cast<s16x4*>(x_bf + (((size_t)s * TT + t) * TB + b) * EMB)[e4] = o;
    }
}

// ---------------------------------------------------------------------------
// xg[m][g] = embed[tok(m)] . W_ih[g] + b_ih[g] + b_hh[g]   (bf16 out)
// m = s*16384 + t*128 + b.  Block = 64M x 256N, A gathered+staged in LDS
// (XOR-swizzled), B from L2-cached W_ihb. 4 waves, wave = 64 rows x 64 cols.
// ---------------------------------------------------------------------------
__global__ __launch_bounds__(256) void k_xproj2(
    const int* __restrict__ tok_h, const int* __restrict__ tok_p,
    const float* __restrict__ embed, const bf16* __restrict__ W_ihb,
    const float* __restrict__ b_ih, const float* __restrict__ b_hh,
    bf16* __restrict__ xg)
{
    __shared__ __align__(16) short As[64][512];
    const int nb = blockIdx.x;      // 0..7 (256-col slabs)
    const int mb = blockIdx.y;      // 0..511 (64-row slabs)
    const int tid = threadIdx.x;
    const int w = tid >> 6, lane = tid & 63, l16 = lane & 15, kq = lane >> 4;
    const int m0 = mb * 64;
    const int s  = m0 >> 14;
    const int tt = (m0 >> 7) & 127;
    const int bbase = m0 & 127;     // 0 or 64
    const int* tp = s ? tok_p : tok_h;

    // stage A: gather 64 embed rows (f32) -> bf16 LDS, swizzled
#pragma unroll
    for (int it = 0; it < 16; ++it) {
        int idx = it * 256 + tid;
        int row = idx >> 6;         // 0..63
        int ch  = idx & 63;         // 16B chunk within row
        int tok = tp[(bbase + row) * TT + tt];
        const float* er = embed + (size_t)tok * EMB + ch * 8;
        float4 v0 = *(const float4*)er;
        float4 v1 = *(const float4*)(er + 4);
        *(short8*)&As[row][(ch ^ (row & 7)) * 8] = pack8(v0, v1);
    }
    __syncthreads();

    const int c0 = nb * 256 + w * 64;
    f32x4 acc[4][4];
#pragma unroll
    for (int mt = 0; mt < 4; ++mt)
#pragma unroll
        for (int nt = 0; nt < 4; ++nt) acc[mt][nt] = (f32x4)0.f;

    for (int kk = 0; kk < 16; ++kk) {
        short8 bfr[4];
#pragma unroll
        for (int nt = 0; nt < 4; ++nt)
            bfr[nt] = *(const short8*)(W_ihb + (size_t)(c0 + nt * 16 + l16) * EMB + kk * 32 + kq * 8);
#pragma unroll
        for (int mt = 0; mt < 4; ++mt) {
            int row = mt * 16 + l16;
            short8 a = *(const short8*)&As[row][(((kk * 4 + kq) ^ (row & 7)) * 8)];
#pragma unroll
            for (int nt = 0; nt < 4; ++nt)
                acc[mt][nt] = __builtin_amdgcn_mfma_f32_16x16x32_bf16(a, bfr[nt], acc[mt][nt], 0, 0, 0);
        }
    }
#pragma unroll
    for (int nt = 0; nt < 4; ++nt) {
        int col = c0 + nt * 16 + l16;
        float bias = b_ih[col] + b_hh[col];
#pragma unroll
        for (int mt = 0; mt < 4; ++mt)
#pragma unroll
            for (int q = 0; q < 4; ++q) {
                int m = m0 + mt * 16 + kq * 4 + q;
                xg[(size_t)m * G4 + col] = f2bf(acc[mt][nt][q] + bias);
            }
    }
}

// ---------------------------------------------------------------------------
// PERSISTENT LSTM v2: 512 blocks = 32 row-groups (16 rows) x 16 col-blocks
// (32 h-cols, all 4 gates). W_hh in REGISTERS (bf16 frags, loaded once).
// xg precomputed (x@W_ih^T+bias). h (bf16 hi/lo) exchanged through the
// LLC via sc0/sc1 loads+stores -> NO cache-wide fences. h staged once per
// block into XOR-swizzled LDS (no wave redundancy). c in registers.
// Barrier: per-rgroup flags via RELAXED agent atomics (sc1), ordering by
// s_waitcnt vmcnt(0) + __syncthreads. Deadlock-free at any occupancy:
// rgroup block-ids are contiguous, so any dispatch prefix contains whole
// rgroups which complete and free CUs.
// ---------------------------------------------------------------------------
__global__ __launch_bounds__(256, 2) void k_persist2(
    const bf16* __restrict__ xg, const float* __restrict__ W_hh,
    bf16* __restrict__ h_hi, bf16* __restrict__ h_lo,
    float* __restrict__ h_fin, int* __restrict__ slots)
{
    __shared__ __align__(16) short hstage[2][16][512];   // 32 KB (hi,lo)
    __shared__ float ga[4][16][32];                      // 8 KB

    const int tid = threadIdx.x;
    const int bid = blockIdx.x;
    const int rg = bid >> 4;          // 0..31 row-group (16 rows)
    const int cb = bid & 15;          // 0..15 col-block (32 h-cols)
    const int w    = tid >> 6;        // gate (i,f,g,o)
    const int lane = tid & 63;
    const int l16 = lane & 15;
    const int kq  = lane >> 4;
    const int j0  = cb * 32;
    const int r0  = rg * 16;
    const int run = rg >> 3;          // 0 hypF, 1 hypB, 2 premF, 3 premB
    const int s   = run >> 1;
    const int dirb = run & 1;
    const int b0  = (rg & 7) * 16;

    // ---- preload W_hh fragments into registers (2 ntiles x 16 kk) ----
    short8 Bf[2][16];
#pragma unroll
    for (int nt = 0; nt < 2; ++nt) {
        const float* wr = W_hh + (size_t)(w * HH + j0 + nt * 16 + l16) * HH;
#pragma unroll
        for (int kk = 0; kk < 16; ++kk) {
            int k = kk * 32 + kq * 8;
            float4 v0 = *(const float4*)(wr + k);
            float4 v1 = *(const float4*)(wr + k + 4);
            Bf[nt][kk] = pack8(v0, v1);
        }
    }

    const int urow = tid >> 4;        // staging/update row 0..15
    const int useg = tid & 15;        // staging segment
    float creg[2] = {0.f, 0.f};
    const size_t HS = (size_t)NROWS * HH;

    for (int t = 0; t < TT; ++t) {
        const int p  = t & 1;
        const int te = dirb ? (TT - 1 - t) : t;

        // ---- stage h (hi+lo) into LDS via LLC-coherent loads ----
        short8 vh[4], vl[4];
        {
            const size_t rb = (size_t)(r0 + urow) * HH + useg * 32;
            unsigned long long ahi = (unsigned long long)(h_hi + (size_t)p * HS + rb);
            unsigned long long alo = (unsigned long long)(h_lo + (size_t)p * HS + rb);
#pragma unroll
            for (int i = 0; i < 4; ++i)
                asm volatile("global_load_dwordx4 %0, %1, off sc0 sc1"
                             : "=v"(vh[i]) : "v"(ahi + i * 16));
#pragma unroll
            for (int i = 0; i < 4; ++i)
                asm volatile("global_load_dwordx4 %0, %1, off sc0 sc1"
                             : "=v"(vl[i]) : "v"(alo + i * 16));
        }

        // acc init from xg (normal cached loads) while the sc1 loads fly
        f32x4 acc[2];
        {
            const bf16* xr = xg + ((size_t)(s * TT + te) * TB) * G4;
#pragma unroll
            for (int nt = 0; nt < 2; ++nt) {
                int col = w * HH + j0 + nt * 16 + l16;
#pragma unroll
                for (int q = 0; q < 4; ++q)
                    acc[nt][q] = bf2f(xr[(size_t)(b0 + kq * 4 + q) * G4 + col]);
            }
        }

        asm volatile("s_waitcnt vmcnt(0)" ::: "memory");
        __builtin_amdgcn_sched_barrier(0);
#pragma unroll
        for (int i = 0; i < 4; ++i) {
            int ch = (useg * 4 + i) ^ (urow & 7);
            *(short8*)&hstage[0][urow][ch * 8] = vh[i];
            *(short8*)&hstage[1][urow][ch * 8] = vl[i];
        }
        __syncthreads();

        // ---- MFMA: gates += (h_lo + h_hi) @ W_hh^T ----
#pragma unroll
        for (int kk = 0; kk < 16; ++kk) {
            int ch = ((kk * 4 + kq) ^ (l16 & 7)) * 8;
            short8 ahi = *(const short8*)&hstage[0][l16][ch];
            short8 alo = *(const short8*)&hstage[1][l16][ch];
#pragma unroll
            for (int nt = 0; nt < 2; ++nt) {
                acc[nt] = __builtin_amdgcn_mfma_f32_16x16x32_bf16(alo, Bf[nt][kk], acc[nt], 0, 0, 0);
                acc[nt] = __builtin_amdgcn_mfma_f32_16x16x32_bf16(ahi, Bf[nt][kk], acc[nt], 0, 0, 0);
            }
        }

        // ---- exchange gate preactivations via LDS ----
#pragma unroll
        for (int nt = 0; nt < 2; ++nt)
#pragma unroll
            for (int q = 0; q < 4; ++q)
                ga[w][kq * 4 + q][nt * 16 + l16] = acc[nt][q];
        __syncthreads();

        // ---- cell update: 2 cells/thread (urow, 2*useg .. +1) ----
        bf16* hob = h_hi + (size_t)(p ^ 1) * HS;
        bf16* lob = h_lo + (size_t)(p ^ 1) * HS;
        unsigned hiw = 0, low = 0;
#pragma unroll
        for (int e = 0; e < 2; ++e) {
            int lc = 2 * useg + e;
            float pi = ga[0][urow][lc];
            float pf = ga[1][urow][lc];
            float pg = ga[2][urow][lc];
            float po = ga[3][urow][lc];
            float si = 1.f / (1.f + expf(-pi));
            float sf = 1.f / (1.f + expf(-pf));
            float so = 1.f / (1.f + expf(-po));
            float tg = tanhf(pg);
            float cn = sf * creg[e] + si * tg;
            float hn = so * tanhf(cn);
            creg[e] = cn;
            bf16 hb16 = f2bf(hn);
            float lof = hn - bf2f(hb16);
            hiw |= (unsigned)__bfloat16_as_ushort(hb16) << (16 * e);
            low |= (unsigned)__bfloat16_as_ushort(f2bf(lof)) << (16 * e);
            if (t == TT - 1) h_fin[(size_t)(r0 + urow) * HH + j0 + lc] = hn;
        }
        {
            size_t rb = (size_t)(r0 + urow) * HH + j0 + 2 * useg;
            unsigned long long ah = (unsigned long long)(hob + rb);
            unsigned long long al = (unsigned long long)(lob + rb);
            asm volatile("global_store_dword %0, %1, off sc0 sc1" :: "v"(ah), "v"(hiw) : "memory");
            asm volatile("global_store_dword %0, %1, off sc0 sc1" :: "v"(al), "v"(low) : "memory");
        }

        if (t == TT - 1) break;

        // ---- row-group barrier (16 col-blocks), LLC flags, no fences ----
        asm volatile("s_waitcnt vmcnt(0)" ::: "memory");
        __syncthreads();
        if (tid == 0)
            __hip_atomic_store(&slots[rg * 16 + cb], t + 1,
                               __ATOMIC_RELAXED, __HIP_MEMORY_SCOPE_AGENT);
        if (tid < 64) {
            int sidx = rg * 16 + l16;
            while (true) {
                int v = (lane < 16)
                    ? __hip_atomic_load(&slots[sidx], __ATOMIC_RELAXED, __HIP_MEMORY_SCOPE_AGENT)
                    : 0x7fffffff;
                if (__all(v >= t + 1)) break;
                __builtin_amdgcn_s_sleep(2);
            }
        }
        __syncthreads();
        __builtin_amdgcn_sched_barrier(0);
    }
}

// ---------------------------------------------------------------------------
// FALLBACK-1: round-4 persistent kernel (proven-correct; slow but fits 47MB)
// ---------------------------------------------------------------------------
__global__ __launch_bounds__(256) void k_persist(
    const bf16* __restrict__ x_bf,
    const float* __restrict__ W_ih, const float* __restrict__ W_hh,
    const float* __restrict__ b_ih, const float* __restrict__ b_hh,
    bf16* __restrict__ h_hi, bf16* __restrict__ h_lo,
    float* __restrict__ h_fin, int* slots)
{
    __shared__ short Wl[4 * 16 * 16 * 64];
    __shared__ float ga[4][64][17];

    const int tid = threadIdx.x;
    const int bx  = blockIdx.x;
    const int mi  = bx & 7;
    const int cj  = bx >> 3;
    const int w    = tid >> 6;
    const int lane = tid & 63;
    const int l16 = lane & 15;
    const int kq  = lane >> 4;
    const int j0  = cj * 16;
    const int r0  = mi * 64;
    const int run = mi >> 1;
    const int s   = run >> 1;
    const int dirb = run & 1;

    {
        int gc  = tid >> 2;
        int g   = gc >> 4, c = gc & 15;
        int kq4 = tid & 3;
        const float* wxr = W_ih + (size_t)(g * HH + j0 + c) * EMB;
        const float* whr = W_hh + (size_t)(g * HH + j0 + c) * HH;
        for (int kb = 0; kb < 16; ++kb) {
            int k  = kq4 * 128 + kb * 8;
            int kk = k >> 5;
            int eq = (k >> 3) & 3;
            float4 x0 = *(const float4*)(wxr + k);
            float4 x1 = *(const float4*)(wxr + k + 4);
            float4 h0 = *(const float4*)(whr + k);
            float4 h1 = *(const float4*)(whr + k + 4);
            int base = ((g * 16 + kk) * 16 + c) * 64;
            int sx = eq ^ (c & 7);
            int sh = (eq + 4) ^ (c & 7);
            *(short8*)&Wl[base + sx * 8] = pack8(x0, x1);
            *(short8*)&Wl[base + sh * 8] = pack8(h0, h1);
        }
    }

    float bsum[4];
    {
        int j = j0 + (tid & 15);
#pragma unroll
        for (int g = 0; g < 4; ++g) bsum[g] = b_ih[g * HH + j] + b_hh[g * HH + j];
    }
    float creg[4] = {0.f, 0.f, 0.f, 0.f};
    __syncthreads();

    const size_t HS = (size_t)NROWS * HH;
    for (int t = 0; t < TT; ++t) {
        const int p  = t & 1;
        const int te = dirb ? (TT - 1 - t) : t;
        const bf16* hb = h_hi + (size_t)p * HS;
        const bf16* lb = h_lo + (size_t)p * HS;
        const bf16* xr0 = x_bf + ((size_t)(s * TT + te) * TB) * EMB;

        f32x4 acc[4];
#pragma unroll
        for (int mt = 0; mt < 4; ++mt) acc[mt] = (f32x4)0.f;

        const bf16 *ph[4], *pl[4], *px[4];
#pragma unroll
        for (int mt = 0; mt < 4; ++mt) {
            int r = r0 + mt * 16 + l16;
            ph[mt] = hb + (size_t)r * HH;
            pl[mt] = lb + (size_t)r * HH;
            px[mt] = xr0 + (size_t)(r & 127) * EMB;
        }

        for (int kk = 0; kk < 16; ++kk) {
            int cbse = ((w * 16 + kk) * 16 + l16) * 64;
            short8 fx = *(const short8*)&Wl[cbse + ((kq ^ (lane & 7)) * 8)];
            short8 fh = *(const short8*)&Wl[cbse + (((kq + 4) ^ (lane & 7)) * 8)];
            int k0 = kk * 32 + kq * 8;
#pragma unroll
            for (int mt = 0; mt < 4; ++mt) {
                short8 ax  = *(const short8*)(px[mt] + k0);
                short8 ahi = *(const short8*)(ph[mt] + k0);
                short8 alo = *(const short8*)(pl[mt] + k0);
                acc[mt] = __builtin_amdgcn_mfma_f32_16x16x32_bf16(ax,  fx, acc[mt], 0, 0, 0);
                acc[mt] = __builtin_amdgcn_mfma_f32_16x16x32_bf16(alo, fh, acc[mt], 0, 0, 0);
                acc[mt] = __builtin_amdgcn_mfma_f32_16x16x32_bf16(ahi, fh, acc[mt], 0, 0, 0);
            }
        }
#pragma unroll
        for (int mt = 0; mt < 4; ++mt)
#pragma unroll
            for (int q = 0; q < 4; ++q)
                ga[w][mt * 16 + kq * 4 + q][l16] = acc[mt][q];
        __syncthreads();

        bf16* hob = h_hi + (size_t)(p ^ 1) * HS;
        bf16* lob = h_lo + (size_t)(p ^ 1) * HS;
        const int colc = tid & 15;
        const int j = j0 + colc;
#pragma unroll
        for (int q = 0; q < 4; ++q) {
            int rl = (tid >> 4) + q * 16;
            int r  = r0 + rl;
            float pi = ga[0][rl][colc] + bsum[0];
            float pf = ga[1][rl][colc] + bsum[1];
            float pg = ga[2][rl][colc] + bsum[2];
            float po = ga[3][rl][colc] + bsum[3];
            float si = 1.f / (1.f + expf(-pi));
            float sf = 1.f / (1.f + expf(-pf));
            float so = 1.f / (1.f + expf(-po));
            float tg = tanhf(pg);
            float cn = sf * creg[q] + si * tg;
            float hn = so * tanhf(cn);
            creg[q] = cn;
            size_t idx = (size_t)r * HH + j;
            bf16 hi = f2bf(hn);
            hob[idx] = hi;
            lob[idx] = f2bf(hn - bf2f(hi));
            if (t == TT - 1) h_fin[idx] = hn;
        }
        if (t == TT - 1) break;

        __syncthreads();
        if (tid == 0)
            __hip_atomic_store(&slots[mi * 32 + cj], t + 1,
                               __ATOMIC_RELEASE, __HIP_MEMORY_SCOPE_AGENT);
        if (tid < 64) {
            const int tgt = t + 1;
            while (true) {
                int v = (lane < 32)
                    ? __hip_atomic_load(&slots[mi * 32 + lane],
                                        __ATOMIC_RELAXED, __HIP_MEMORY_SCOPE_AGENT)
                    : tgt;
                if (__all(v >= tgt)) break;
                __builtin_amdgcn_s_sleep(1);
            }
            __builtin_amdgcn_fence(__ATOMIC_ACQUIRE, "agent");
        }
        __syncthreads();
    }
}

// ---------------------------------------------------------------------------
// FALLBACK-2: per-step kernel (round-3), x gathered from embed
// ---------------------------------------------------------------------------
template<int GATH>
__global__ __launch_bounds__(256) void k_step(
    const bf16* __restrict__ x_bf, const float* __restrict__ embed,
    const int* __restrict__ tok_h, const int* __restrict__ tok_p,
    const bf16* __restrict__ W_ihb, const bf16* __restrict__ W_hhb,
    const float* __restrict__ b_ih, const float* __restrict__ b_hh,
    const bf16* __restrict__ h_hi_in, const bf16* __restrict__ h_lo_in,
    bf16* __restrict__ h_hi_out, bf16* __restrict__ h_lo_out,
    float* __restrict__ c_buf, float* __restrict__ h_fin, int t)
{
    __shared__ float lds[4][64][17];

    const int blk = blockIdx.x;
    const int mi = blk >> 5;
    const int ji = blk & 31;
    const int w    = threadIdx.x >> 6;
    const int lane = threadIdx.x & 63;
    const int l16 = lane & 15;
    const int kq  = lane >> 4;

    const int run = mi >> 1;
    const int s   = run >> 1;
    const int te  = (run & 1) ? (TT - 1 - t) : t;
    const int r0  = mi * 64;

    const bf16*  hhp[4];
    const bf16*  hlp[4];
    const bf16*  xbp[4];
    const float* xfp[4];
#pragma unroll
    for (int mt = 0; mt < 4; ++mt) {
        int r = r0 + mt * 16 + l16;
        hhp[mt] = h_hi_in + (size_t)r * HH;
        hlp[mt] = h_lo_in + (size_t)r * HH;
        int b = r & 127;
        if (GATH) {
            xbp[mt] = x_bf + (((size_t)s * TT + te) * TB + b) * EMB;
        } else {
            int tok = (s ? tok_p : tok_h)[b * TT + te];
            xfp[mt] = embed + (size_t)tok * EMB;
        }
    }

    const int gcol = w * HH + ji * 16 + l16;
    const bf16* wh = W_hhb + (size_t)gcol * HH;
    const bf16* wx = W_ihb + (size_t)gcol * EMB;

    f32x4 acc[4];
#pragma unroll
    for (int mt = 0; mt < 4; ++mt) acc[mt] = (f32x4)0.f;

    for (int kk = 0; kk < HH / 32; ++kk) {
        const int k0 = kk * 32 + kq * 8;
        short8 bwh = *reinterpret_cast<const short8*>(wh + k0);
        short8 bwx = *reinterpret_cast<const short8*>(wx + k0);
#pragma unroll
        for (int mt = 0; mt < 4; ++mt) {
            short8 ax;
            if (GATH) {
                ax = *reinterpret_cast<const short8*>(xbp[mt] + k0);
            } else {
                float4 v0 = *reinterpret_cast<const float4*>(xfp[mt] + k0);
                float4 v1 = *reinterpret_cast<const float4*>(xfp[mt] + k0 + 4);
                ax = pack8(v0, v1);
            }
            short8 ahi = *reinterpret_cast<const short8*>(hhp[mt] + k0);
            short8 alo = *reinterpret_cast<const short8*>(hlp[mt] + k0);
            acc[mt] = __builtin_amdgcn_mfma_f32_16x16x32_bf16(ax,  bwx, acc[mt], 0, 0, 0);
            acc[mt] = __builtin_amdgcn_mfma_f32_16x16x32_bf16(alo, bwh, acc[mt], 0, 0, 0);
            acc[mt] = __builtin_amdgcn_mfma_f32_16x16x32_bf16(ahi, bwh, acc[mt], 0, 0, 0);
        }
    }
#pragma unroll
    for (int mt = 0; mt < 4; ++mt)
#pragma unroll
        for (int q = 0; q < 4; ++q)
            lds[w][mt * 16 + kq * 4 + q][l16] = acc[mt][q];
    __syncthreads();

    const int tid = threadIdx.x;
#pragma unroll
    for (int q = 0; q < 4; ++q) {
        int cell = tid + q * 256;
        int rl  = cell >> 4;
        int col = cell & 15;
        int r = r0 + rl;
        int j = ji * 16 + col;

        float pi = lds[0][rl][col] + b_ih[j]          + b_hh[j];
        float pf = lds[1][rl][col] + b_ih[HH + j]     + b_hh[HH + j];
        float pg = lds[2][rl][col] + b_ih[2 * HH + j] + b_hh[2 * HH + j];
        float po = lds[3][rl][col] + b_ih[3 * HH + j] + b_hh[3 * HH + j];

        float si = 1.f / (1.f + expf(-pi));
        float sf = 1.f / (1.f + expf(-pf));
        float so = 1.f / (1.f + expf(-po));
        float tg = tanhf(pg);

        size_t idx = (size_t)r * HH + j;
        float cn = sf * c_buf[idx] + si * tg;
        float hn = so * tanhf(cn);
        c_buf[idx] = cn;

        bf16 hi = f2bf(hn);
        h_hi_out[idx] = hi;
        h_lo_out[idx] = f2bf(hn - bf2f(hi));
        if (t == TT - 1) h_fin[idx] = hn;
    }
}

// ---------------------------------------------------------------------------
// features [hyp, prem, prem-hyp, hyp*prem] + LayerNorm(4096); block per row
// ---------------------------------------------------------------------------
__global__ __launch_bounds__(256) void k_feat_ln0(
    const float* __restrict__ h_fin, const float* __restrict__ g,
    const float* __restrict__ be, bf16* __restrict__ f_out)
{
    const int b = blockIdx.x;
    const int tid = threadIdx.x;
    float v[16];
    float s = 0.f, sq = 0.f;
#pragma unroll
    for (int i = 0; i < 16; ++i) {
        int e = i * 256 + tid;
        int region = e >> 10;
        int idx = e & 1023;
        int runh = (idx < 512) ? 0 : 1;
        int jj = idx & 511;
        float hy = h_fin[((size_t)(runh * TB + b)) * HH + jj];
        float pr = h_fin[((size_t)((runh + 2) * TB + b)) * HH + jj];
        float val = (region == 0) ? hy : (region == 1) ? pr
                  : (region == 2) ? (pr - hy) : (hy * pr);
        v[i] = val;
        s += val;
        sq += val * val;
    }
    __shared__ float shs[4], shq[4];
    for (int o = 32; o; o >>= 1) { s += __shfl_down(s, o); sq += __shfl_down(sq, o); }
    int w = tid >> 6, lane = tid & 63;
    if (!lane) { shs[w] = s; shq[w] = sq; }
    __syncthreads();
    s  = shs[0] + shs[1] + shs[2] + shs[3];
    sq = shq[0] + shq[1] + shq[2] + shq[3];
    float mean = s / (float)F4;
    float var  = sq / (float)F4 - mean * mean;
    float rstd = rsqrtf(var + 1e-6f);
#pragma unroll
    for (int i = 0; i < 16; ++i) {
        int e = i * 256 + tid;
        float nv = (v[i] - mean) * rstd * g[e] + be[e];
        f_out[(size_t)b * F4 + e] = f2bf(nv);
    }
}

// ---------------------------------------------------------------------------
// split-K MLP partial GEMM + reduce
// ---------------------------------------------------------------------------
template<int KTOT, int NCH>
__global__ __launch_bounds__(256) void k_mlp_sk(
    const bf16* __restrict__ A, const float* __restrict__ Bw,
    float* __restrict__ part)
{
    const int KC = KTOT / NCH;
    const int nb = blockIdx.x, mb = blockIdx.y, kc = blockIdx.z;
    const int w    = threadIdx.x >> 6;
    const int lane = threadIdx.x & 63;
    const int wr = w >> 1, wc = w & 1;
    const int l16 = lane & 15;
    const int kq  = lane >> 4;
    const int m0 = mb * 64 + wr * 32;
    const int c0 = nb * 64 + wc * 32;

    f32x4 acc[2][2];
#pragma unroll
    for (int i = 0; i < 2; ++i)
#pragma unroll
        for (int j = 0; j < 2; ++j) acc[i][j] = (f32x4)0.f;

    for (int kk = kc * (KC / 32); kk < (kc + 1) * (KC / 32); ++kk) {
        const int k0 = kk * 32 + kq * 8;
        short8 a[2], bb[2];
#pragma unroll
        for (int i = 0; i < 2; ++i)
            a[i] = *reinterpret_cast<const short8*>(A + (size_t)(m0 + i * 16 + l16) * KTOT + k0);
#pragma unroll
        for (int j = 0; j < 2; ++j) {
            const float* bp = Bw + (size_t)(c0 + j * 16 + l16) * KTOT + k0;
            float4 v0 = *reinterpret_cast<const float4*>(bp);
            float4 v1 = *reinterpret_cast<const float4*>(bp + 4);
            bb[j] = pack8(v0, v1);
        }
#pragma unroll
        for (int i = 0; i < 2; ++i)
#pragma unroll
            for (int j = 0; j < 2; ++j)
                acc[i][j] = __builtin_amdgcn_mfma_f32_16x16x32_bf16(a[i], bb[j], acc[i][j], 0, 0, 0);
    }
#pragma unroll
    for (int i = 0; i < 2; ++i)
#pragma unroll
        for (int j = 0; j < 2; ++j) {
            int gg = c0 + j * 16 + l16;
#pragma unroll
            for (int q = 0; q < 4; ++q) {
                int m = m0 + i * 16 + kq * 4 + q;
                part[((size_t)kc * TB + m) * HD + gg] = acc[i][j][q];
            }
        }
}

template<int NCH>
__global__ __launch_bounds__(256) void k_red(
    const float* __restrict__ part, const float* __restrict__ bias,
    float* __restrict__ act)
{
    int i = blockIdx.x * 256 + threadIdx.x;
    if (i < TB * HD) {
        float s = bias[i & (HD - 1)];
#pragma unroll
        for (int c = 0; c < NCH; ++c) s += part[(size_t)c * TB * HD + i];
        act[i] = fmaxf(s, 0.f);
    }
}

// ---------------------------------------------------------------------------
// LayerNorm over 1024 (f32 in, bf16 out)
// ---------------------------------------------------------------------------
__global__ __launch_bounds__(256) void k_ln(
    const float* __restrict__ x, const float* __restrict__ g,
    const float* __restrict__ be, bf16* __restrict__ out)
{
    const int b = blockIdx.x;
    const int tid = threadIdx.x;
    float v[4];
    float s = 0.f, sq = 0.f;
#pragma unroll
    for (int i = 0; i < 4; ++i) {
        int e = i * 256 + tid;
        float val = x[(size_t)b * HD + e];
        v[i] = val; s += val; sq += val * val;
    }
    __shared__ float shs[4], shq[4];
    for (int o = 32; o; o >>= 1) { s += __shfl_down(s, o); sq += __shfl_down(sq, o); }
    int w = tid >> 6, lane = tid & 63;
    if (!lane) { shs[w] = s; shq[w] = sq; }
    __syncthreads();
    s  = shs[0] + shs[1] + shs[2] + shs[3];
    sq = shq[0] + shq[1] + shq[2] + shq[3];
    float mean = s / (float)HD;
    float var  = sq / (float)HD - mean * mean;
    float rstd = rsqrtf(var + 1e-6f);
#pragma unroll
    for (int i = 0; i < 4; ++i) {
        int e = i * 256 + tid;
        float nv = (v[i] - mean) * rstd * g[e] + be[e];
        out[(size_t)b * HD + e] = f2bf(nv);
    }
}

// ---------------------------------------------------------------------------
// output projection [128,3]
// ---------------------------------------------------------------------------
__global__ __launch_bounds__(256) void k_out(
    const bf16* __restrict__ x, const float* __restrict__ Wt,
    const float* __restrict__ bias, float* __restrict__ out)
{
    const int b = blockIdx.x;
    const int tid = threadIdx.x;
    float p0 = 0.f, p1 = 0.f, p2 = 0.f;
    for (int k = tid; k < HD; k += 256) {
        float xv = bf2f(x[(size_t)b * HD + k]);
        p0 += xv * Wt[k];
        p1 += xv * Wt[HD + k];
        p2 += xv * Wt[2 * HD + k];
    }
    for (int o = 32; o; o >>= 1) {
        p0 += __shfl_down(p0, o);
        p1 += __shfl_down(p1, o);
        p2 += __shfl_down(p2, o);
    }
    __shared__ float sh[4][3];
    int w = tid >> 6, lane = tid & 63;
    if (!lane) { sh[w][0] = p0; sh[w][1] = p1; sh[w][2] = p2; }
    __syncthreads();
    if (tid < 3) {
        out[b * 3 + tid] = sh[0][tid] + sh[1][tid] + sh[2][tid] + sh[3][tid] + bias[tid];
    }
}

// ---------------------------------------------------------------------------
extern "C" void kernel_launch(void* const* d_in, const int* in_sizes, int n_in,
                              void* d_out, int out_size, void* d_ws, size_t ws_size,
                              hipStream_t stream)
{
    const int*   tok_h  = (const int*)  d_in[0];
    const int*   tok_p  = (const int*)  d_in[1];
    const float* embed  = (const float*)d_in[2];
    const float* W_ih   = (const float*)d_in[3];
    const float* W_hh   = (const float*)d_in[4];
    const float* b_ih   = (const float*)d_in[5];
    const float* b_hh   = (const float*)d_in[6];
    const float* mlp1_W = (const float*)d_in[7];
    const float* mlp1_b = (const float*)d_in[8];
    const float* mlp2_W = (const float*)d_in[9];
    const float* mlp2_b = (const float*)d_in[10];
    const float* out_W  = (const float*)d_in[11];
    const float* out_b  = (const float*)d_in[12];
    const float* ln0_g  = (const float*)d_in[13];
    const float* ln0_b  = (const float*)d_in[14];
    const float* ln1_g  = (const float*)d_in[15];
    const float* ln1_b  = (const float*)d_in[16];
    const float* ln2_g  = (const float*)d_in[17];
    const float* ln2_b  = (const float*)d_in[18];

    char* ws = (char*)d_ws;
    size_t off = 0;
    bf16*  f_ln0 = (bf16*)(ws + off);  off += (size_t)TB * F4 * 2;            // 1 MB
    float* part  = (float*)(ws + off); off += (size_t)8 * TB * HD * 4;        // 4 MB
    float* act1  = (float*)(ws + off); off += (size_t)TB * HD * 4;
    bf16*  f_ln1 = (bf16*)(ws + off);  off += (size_t)TB * HD * 2;
    float* act2  = (float*)(ws + off); off += (size_t)TB * HD * 4;
    bf16*  f_ln2 = (bf16*)(ws + off);  off += (size_t)TB * HD * 2;
    float* h_fin = (float*)(ws + off); off += (size_t)NROWS * HH * 4;         // 1 MB
    bf16*  h_hi  = (bf16*)(ws + off);  off += (size_t)2 * NROWS * HH * 2;     // 1 MB
    bf16*  h_lo  = (bf16*)(ws + off);  off += (size_t)2 * NROWS * HH * 2;     // 1 MB
    int*   slots = (int*)(ws + off);   off += 4096;
    float* c_buf = (float*)(ws + off); off += (size_t)NROWS * HH * 4;         // 1 MB
    bf16*  W_ihb = (bf16*)(ws + off);  off += (size_t)G4 * EMB * 2;           // 2 MB
    bf16*  W_hhb = (bf16*)(ws + off);  off += (size_t)G4 * HH * 2;            // 2 MB
    // big region: UNION of xg (primary, 128 MB) and x_bf (fallbacks, 32 MB)
    bf16*  xg   = (bf16*)(ws + off);
    bf16*  x_bf = (bf16*)(ws + off);
    const size_t need_primary = off + (size_t)2 * TT * TB * G4 * 2;   // +128 MB
    const size_t need_f1      = off + (size_t)2 * TT * TB * EMB * 2;  // +32 MB

    // zero h (both parities, hi+lo) + slots (contiguous region)
    (void)hipMemsetAsync(h_hi, 0, (size_t)4 * NROWS * HH * 2 + 4096, stream);

    const size_t HS = (size_t)NROWS * HH;
    if (ws_size >= need_primary) {
        k_cvt<<<512, 256, 0, stream>>>(W_ih, W_ihb, G4 * EMB / 4);
        k_xproj2<<<dim3(8, 512), 256, 0, stream>>>(tok_h, tok_p, embed, W_ihb,
                                                   b_ih, b_hh, xg);
        k_persist2<<<512, 256, 0, stream>>>(xg, W_hh, h_hi, h_lo, h_fin, slots);
    } else if (ws_size >= need_f1) {
        k_gather<<<4096, 256, 0, stream>>>(tok_h, tok_p, embed, x_bf);
        void* args[] = {(void*)&x_bf, (void*)&W_ih, (void*)&W_hh,
                        (void*)&b_ih, (void*)&b_hh,
                        (void*)&h_hi, (void*)&h_lo, (void*)&h_fin, (void*)&slots};
        (void)hipLaunchCooperativeKernel((void*)k_persist, dim3(256), dim3(256),
                                         args, 0, stream);
    } else {
        (void)hipMemsetAsync(c_buf, 0, (size_t)NROWS * HH * 4, stream);
        k_cvt<<<512, 256, 0, stream>>>(W_ih, W_ihb, G4 * EMB / 4);
        k_cvt<<<512, 256, 0, stream>>>(W_hh, W_hhb, G4 * HH / 4);
        for (int t = 0; t < TT; ++t) {
            int p = t & 1;
            k_step<0><<<256, 256, 0, stream>>>(x_bf, embed, tok_h, tok_p,
                W_ihb, W_hhb, b_ih, b_hh,
                h_hi + (size_t)p * HS, h_lo + (size_t)p * HS,
                h_hi + (size_t)(p ^ 1) * HS, h_lo + (size_t)(p ^ 1) * HS,
                c_buf, h_fin, t);
        }
    }

    // head
    k_feat_ln0<<<TB, 256, 0, stream>>>(h_fin, ln0_g, ln0_b, f_ln0);
    k_mlp_sk<F4, 8><<<dim3(16, 2, 8), 256, 0, stream>>>(f_ln0, mlp1_W, part);
    k_red<8><<<512, 256, 0, stream>>>(part, mlp1_b, act1);
    k_ln<<<TB, 256, 0, stream>>>(act1, ln1_g, ln1_b, f_ln1);
    k_mlp_sk<HD, 4><<<dim3(16, 2, 4), 256, 0, stream>>>(f_ln1, mlp2_W, part);
    k_red<4><<<512, 256, 0, stream>>>(part, mlp2_b, act2);
    k_ln<<<TB, 256, 0, stream>>>(act2, ln2_g, ln2_b, f_ln2);
    k_out<<<TB, 256, 0, stream>>>(f_ln2, out_W, out_b, (float*)d_out);
}

// Round 6
// 1014.901 us; speedup vs baseline: 4.2701x; 1.1016x over previous
//
#include <hip/hip_runtime.h>
#include <hip/hip_bf16.h>

typedef __hip_bfloat16 bf16;
typedef __attribute__((ext_vector_type(8))) short short8;
typedef __attribute__((ext_vector_type(4))) short s16x4;
typedef __attribute__((ext_vector_type(4))) float f32x4;
typedef __attribute__((ext_vector_type(2))) float f32x2;

#define TB 128      // batch
#define TT 128      // time
#define EMB 512     // embed dim
#define HH 512      // per-direction hidden
#define G4 2048     // 4*HH gate dim
#define NROWS 512   // 4 runs * 128 batch
#define F4 4096     // feature dim
#define HD 1024     // mlp hidden

__device__ __forceinline__ bf16 f2bf(float x){ return __float2bfloat16(x); }
__device__ __forceinline__ float bf2f(bf16 x){ return __bfloat162float(x); }

__device__ __forceinline__ short8 pack8(float4 a, float4 b){
    short8 r;
    r[0] = (short)__bfloat16_as_ushort(f2bf(a.x));
    r[1] = (short)__bfloat16_as_ushort(f2bf(a.y));
    r[2] = (short)__bfloat16_as_ushort(f2bf(a.z));
    r[3] = (short)__bfloat16_as_ushort(f2bf(a.w));
    r[4] = (short)__bfloat16_as_ushort(f2bf(b.x));
    r[5] = (short)__bfloat16_as_ushort(f2bf(b.y));
    r[6] = (short)__bfloat16_as_ushort(f2bf(b.z));
    r[7] = (short)__bfloat16_as_ushort(f2bf(b.w));
    return r;
}

// ---------------------------------------------------------------------------
// f32 -> bf16 conversion
// ---------------------------------------------------------------------------
__global__ __launch_bounds__(256) void k_cvt(const float* __restrict__ src,
                                             bf16* __restrict__ dst, int n4)
{
    for (int i = blockIdx.x * 256 + threadIdx.x; i < n4; i += gridDim.x * 256) {
        float4 v = reinterpret_cast<const float4*>(src)[i];
        s16x4 o;
        o[0] = (short)__bfloat16_as_ushort(f2bf(v.x));
        o[1] = (short)__bfloat16_as_ushort(f2bf(v.y));
        o[2] = (short)__bfloat16_as_ushort(f2bf(v.z));
        o[3] = (short)__bfloat16_as_ushort(f2bf(v.w));
        reinterpret_cast<s16x4*>(dst)[i] = o;
    }
}

// ---------------------------------------------------------------------------
// Gather embed rows to bf16 x_bf[s][t][b][e]  (fallback paths only)
// ---------------------------------------------------------------------------
__global__ __launch_bounds__(256) void k_gather(
    const int* __restrict__ tok_h, const int* __restrict__ tok_p,
    const float* __restrict__ embed, bf16* __restrict__ x_bf)
{
    const int total4 = 2 * TT * TB * (EMB / 4);
    for (int g = blockIdx.x * 256 + threadIdx.x; g < total4; g += gridDim.x * 256) {
        int e4 = g & (EMB / 4 - 1);
        int b  = (g >> 7) & 127;
        int t  = (g >> 14) & 127;
        int s  = g >> 21;
        int tok = (s ? tok_p : tok_h)[b * TT + t];
        float4 v = reinterpret_cast<const float4*>(embed + (size_t)tok * EMB)[e4];
        s16x4 o;
        o[0] = (short)__bfloat16_as_ushort(f2bf(v.x));
        o[1] = (short)__bfloat16_as_ushort(f2bf(v.y));
        o[2] = (short)__bfloat16_as_ushort(f2bf(v.z));
        o[3] = (short)__bfloat16_as_ushort(f2bf(v.w));
        reinterpret_cast<s16x4*>(x_bf + (((size_t)s * TT + t) * TB + b) * EMB)[e4] = o;
    }
}

// ---------------------------------------------------------------------------
// xg[m][g] = embed[tok(m)] . W_ih[g] + b_ih[g] + b_hh[g]   (bf16 out)
// grid (512, 8): mb = blockIdx.x (FASTEST -> same-A blocks co-XCD), nb = y.
// ---------------------------------------------------------------------------
__global__ __launch_bounds__(256) void k_xproj2(
    const int* __restrict__ tok_h, const int* __restrict__ tok_p,
    const float* __restrict__ embed, const bf16* __restrict__ W_ihb,
    const float* __restrict__ b_ih, const float* __restrict__ b_hh,
    bf16* __restrict__ xg)
{
    __shared__ __align__(16) short As[64][512];
    const int mb = blockIdx.x;      // 0..511 (64-row slabs)  [fastest dim]
    const int nb = blockIdx.y;      // 0..7 (256-col slabs)
    const int tid = threadIdx.x;
    const int w = tid >> 6, lane = tid & 63, l16 = lane & 15, kq = lane >> 4;
    const int m0 = mb * 64;
    const int s  = m0 >> 14;
    const int tt = (m0 >> 7) & 127;
    const int bbase = m0 & 127;     // 0 or 64
    const int* tp = s ? tok_p : tok_h;

    // stage A: gather 64 embed rows (f32) -> bf16 LDS, swizzled
#pragma unroll
    for (int it = 0; it < 16; ++it) {
        int idx = it * 256 + tid;
        int row = idx >> 6;         // 0..63
        int ch  = idx & 63;         // 16B chunk within row
        int tok = tp[(bbase + row) * TT + tt];
        const float* er = embed + (size_t)tok * EMB + ch * 8;
        float4 v0 = *(const float4*)er;
        float4 v1 = *(const float4*)(er + 4);
        *(short8*)&As[row][(ch ^ (row & 7)) * 8] = pack8(v0, v1);
    }
    __syncthreads();

    const int c0 = nb * 256 + w * 64;
    f32x4 acc[4][4];
#pragma unroll
    for (int mt = 0; mt < 4; ++mt)
#pragma unroll
        for (int nt = 0; nt < 4; ++nt) acc[mt][nt] = (f32x4)0.f;

    for (int kk = 0; kk < 16; ++kk) {
        short8 bfr[4];
#pragma unroll
        for (int nt = 0; nt < 4; ++nt)
            bfr[nt] = *(const short8*)(W_ihb + (size_t)(c0 + nt * 16 + l16) * EMB + kk * 32 + kq * 8);
#pragma unroll
        for (int mt = 0; mt < 4; ++mt) {
            int row = mt * 16 + l16;
            short8 a = *(const short8*)&As[row][(((kk * 4 + kq) ^ (row & 7)) * 8)];
#pragma unroll
            for (int nt = 0; nt < 4; ++nt)
                acc[mt][nt] = __builtin_amdgcn_mfma_f32_16x16x32_bf16(a, bfr[nt], acc[mt][nt], 0, 0, 0);
        }
    }
#pragma unroll
    for (int nt = 0; nt < 4; ++nt) {
        int col = c0 + nt * 16 + l16;
        float bias = b_ih[col] + b_hh[col];
#pragma unroll
        for (int mt = 0; mt < 4; ++mt)
#pragma unroll
            for (int q = 0; q < 4; ++q) {
                int m = m0 + mt * 16 + kq * 4 + q;
                xg[(size_t)m * G4 + col] = f2bf(acc[mt][nt][q] + bias);
            }
    }
}

// ---------------------------------------------------------------------------
// PERSISTENT LSTM v3: 256 blocks = 32 rgroups(16 rows) x 8 cbs(64 h-cols),
// 512 threads (8 waves). Per block: all 4 gates for 16r x 64c. W_hh in
// registers (Bf[2][16] per wave = 128 VGPR). h exchanged as ONE f32 stream
// through the LLC (sc0/sc1), hi/lo split in VALU -> LDS. c in registers.
// Halves round-5's exchange traffic (cbs 16 -> 8). No cache-wide fences.
// Block ids cb-fastest: any dispatch prefix = whole rgroups (deadlock-free).
// ---------------------------------------------------------------------------
__global__ __launch_bounds__(512, 1) void k_persist3(
    const bf16* __restrict__ xg, const float* __restrict__ W_hh,
    const float* __restrict__ b_ih, const float* __restrict__ b_hh,
    float* __restrict__ h_f32, float* __restrict__ h_fin,
    int* __restrict__ slots)
{
    __shared__ __align__(16) short hstage[2][16][512];   // 32 KB (hi,lo)
    __shared__ float ga[16][16][17];                     // 17.4 KB

    const int tid = threadIdx.x;
    const int bid = blockIdx.x;
    const int rg = bid >> 3;          // 0..31
    const int cb = bid & 7;           // 0..7
    const int w = tid >> 6, lane = tid & 63, l16 = lane & 15, kq = lane >> 4;
    const int j0 = cb * 64;
    const int r0 = rg * 16;
    const int run = rg >> 3;          // 0 hypF, 1 hypB, 2 premF, 3 premB
    const int s = run >> 1, dirb = run & 1;
    const int b0 = (rg & 7) * 16;

    // ---- W_hh register frags: wave w owns ntiles 2w, 2w+1 ----
    short8 Bf[2][16];
#pragma unroll
    for (int nt = 0; nt < 2; ++nt) {
        int n = 2 * w + nt;
        int gcol = (n >> 2) * HH + j0 + (n & 3) * 16 + l16;
        const float* wr = W_hh + (size_t)gcol * HH;
#pragma unroll
        for (int kk = 0; kk < 16; ++kk) {
            float4 v0 = *(const float4*)(wr + kk * 32 + kq * 8);
            float4 v1 = *(const float4*)(wr + kk * 32 + kq * 8 + 4);
            Bf[nt][kk] = pack8(v0, v1);
        }
    }

    const int urow = tid >> 5;        // 0..15 (row for staging/update)
    const int jseg = tid & 31;        // 16-f32 segment / 2-cell column pair
    float bsum[2][4];
#pragma unroll
    for (int e = 0; e < 2; ++e)
#pragma unroll
        for (int g = 0; g < 4; ++g) {
            int j = g * HH + j0 + jseg * 2 + e;
            bsum[e][g] = b_ih[j] + b_hh[j];
        }
    float creg[2] = {0.f, 0.f};
    const size_t HSF = (size_t)NROWS * HH;

    for (int t = 0; t < TT; ++t) {
        const int p  = t & 1;
        const int te = dirb ? (TT - 1 - t) : t;

        // ---- load 16 f32 of h via LLC-coherent loads ----
        f32x4 hv[4];
        {
            unsigned long long a = (unsigned long long)(
                h_f32 + (size_t)p * HSF + (size_t)(r0 + urow) * HH + jseg * 16);
#pragma unroll
            for (int i = 0; i < 4; ++i)
                asm volatile("global_load_dwordx4 %0, %1, off sc0 sc1"
                             : "=v"(hv[i]) : "v"(a + i * 16));
        }

        // acc init from xg (normal cached) while sc loads fly
        f32x4 acc[2];
        {
            const bf16* xr = xg + ((size_t)(s * TT + te) * TB) * G4;
#pragma unroll
            for (int nt = 0; nt < 2; ++nt) {
                int n = 2 * w + nt;
                int gcol = (n >> 2) * HH + j0 + (n & 3) * 16 + l16;
#pragma unroll
                for (int q = 0; q < 4; ++q)
                    acc[nt][q] = bf2f(xr[(size_t)(b0 + kq * 4 + q) * G4 + gcol]);
            }
        }

        asm volatile("s_waitcnt vmcnt(0)" ::: "memory");
        __builtin_amdgcn_sched_barrier(0);

        // ---- split f32 -> hi/lo bf16, stage to LDS (XOR-swizzled) ----
#pragma unroll
        for (int half = 0; half < 2; ++half) {
            short8 hi, lo;
#pragma unroll
            for (int i2 = 0; i2 < 8; ++i2) {
                float v = hv[half * 2 + (i2 >> 2)][i2 & 3];
                bf16 hb = f2bf(v);
                hi[i2] = (short)__bfloat16_as_ushort(hb);
                lo[i2] = (short)__bfloat16_as_ushort(f2bf(v - bf2f(hb)));
            }
            int ch = (2 * jseg + half) ^ (urow & 7);
            *(short8*)&hstage[0][urow][ch * 8] = hi;
            *(short8*)&hstage[1][urow][ch * 8] = lo;
        }
        __syncthreads();

        // ---- MFMA: gates += (h_lo + h_hi) @ W_hh^T ----
#pragma unroll
        for (int kk = 0; kk < 16; ++kk) {
            int ch = ((kk * 4 + kq) ^ (l16 & 7)) * 8;
            short8 ahi = *(const short8*)&hstage[0][l16][ch];
            short8 alo = *(const short8*)&hstage[1][l16][ch];
#pragma unroll
            for (int nt = 0; nt < 2; ++nt) {
                acc[nt] = __builtin_amdgcn_mfma_f32_16x16x32_bf16(alo, Bf[nt][kk], acc[nt], 0, 0, 0);
                acc[nt] = __builtin_amdgcn_mfma_f32_16x16x32_bf16(ahi, Bf[nt][kk], acc[nt], 0, 0, 0);
            }
        }

        // ---- exchange gate preactivations ----
#pragma unroll
        for (int nt = 0; nt < 2; ++nt)
#pragma unroll
            for (int q = 0; q < 4; ++q)
                ga[2 * w + nt][kq * 4 + q][l16] = acc[nt][q];
        __syncthreads();

        // ---- cell update: 2 cells (row urow, cols jseg*2, +1) ----
        float hn2[2];
#pragma unroll
        for (int e = 0; e < 2; ++e) {
            int jc = jseg * 2 + e;
            int sub = jc >> 4, c15 = jc & 15;
            float pi = ga[0 + sub][urow][c15]  + bsum[e][0];
            float pf = ga[4 + sub][urow][c15]  + bsum[e][1];
            float pg = ga[8 + sub][urow][c15]  + bsum[e][2];
            float po = ga[12 + sub][urow][c15] + bsum[e][3];
            float si = 1.f / (1.f + expf(-pi));
            float sf = 1.f / (1.f + expf(-pf));
            float so = 1.f / (1.f + expf(-po));
            float tg = tanhf(pg);
            float cn = sf * creg[e] + si * tg;
            float hn = so * tanhf(cn);
            creg[e] = cn;
            hn2[e] = hn;
        }
        {
            unsigned long long a = (unsigned long long)(
                h_f32 + (size_t)(p ^ 1) * HSF + (size_t)(r0 + urow) * HH + j0 + jseg * 2);
            f32x2 val; val[0] = hn2[0]; val[1] = hn2[1];
            asm volatile("global_store_dwordx2 %0, %1, off sc0 sc1"
                         :: "v"(a), "v"(val) : "memory");
            if (t == TT - 1) {
                size_t fb = (size_t)(r0 + urow) * HH + j0 + jseg * 2;
                h_fin[fb] = hn2[0];
                h_fin[fb + 1] = hn2[1];
            }
        }
        if (t == TT - 1) break;

        // ---- row-group barrier (8 col-blocks), LLC flags, no fences ----
        asm volatile("s_waitcnt vmcnt(0)" ::: "memory");
        __syncthreads();
        if (tid == 0)
            __hip_atomic_store(&slots[rg * 8 + cb], t + 1,
                               __ATOMIC_RELAXED, __HIP_MEMORY_SCOPE_AGENT);
        if (tid < 64) {
            int sidx = rg * 8 + (lane & 7);
            while (true) {
                int v = (lane < 8)
                    ? __hip_atomic_load(&slots[sidx], __ATOMIC_RELAXED, __HIP_MEMORY_SCOPE_AGENT)
                    : 0x7fffffff;
                if (__all(v >= t + 1)) break;
                __builtin_amdgcn_s_sleep(2);
            }
        }
        __syncthreads();
        __builtin_amdgcn_sched_barrier(0);
    }
}

// ---------------------------------------------------------------------------
// FALLBACK-1: round-4 cooperative persistent kernel (47 MB ws)
// ---------------------------------------------------------------------------
__global__ __launch_bounds__(256) void k_persist(
    const bf16* __restrict__ x_bf,
    const float* __restrict__ W_ih, const float* __restrict__ W_hh,
    const float* __restrict__ b_ih, const float* __restrict__ b_hh,
    bf16* __restrict__ h_hi, bf16* __restrict__ h_lo,
    float* __restrict__ h_fin, int* slots)
{
    __shared__ short Wl[4 * 16 * 16 * 64];
    __shared__ float ga[4][64][17];

    const int tid = threadIdx.x;
    const int bx  = blockIdx.x;
    const int mi  = bx & 7;
    const int cj  = bx >> 3;
    const int w    = tid >> 6;
    const int lane = tid & 63;
    const int l16 = lane & 15;
    const int kq  = lane >> 4;
    const int j0  = cj * 16;
    const int r0  = mi * 64;
    const int run = mi >> 1;
    const int s   = run >> 1;
    const int dirb = run & 1;

    {
        int gc  = tid >> 2;
        int g   = gc >> 4, c = gc & 15;
        int kq4 = tid & 3;
        const float* wxr = W_ih + (size_t)(g * HH + j0 + c) * EMB;
        const float* whr = W_hh + (size_t)(g * HH + j0 + c) * HH;
        for (int kb = 0; kb < 16; ++kb) {
            int k  = kq4 * 128 + kb * 8;
            int kk = k >> 5;
            int eq = (k >> 3) & 3;
            float4 x0 = *(const float4*)(wxr + k);
            float4 x1 = *(const float4*)(wxr + k + 4);
            float4 h0 = *(const float4*)(whr + k);
            float4 h1 = *(const float4*)(whr + k + 4);
            int base = ((g * 16 + kk) * 16 + c) * 64;
            int sx = eq ^ (c & 7);
            int sh = (eq + 4) ^ (c & 7);
            *(short8*)&Wl[base + sx * 8] = pack8(x0, x1);
            *(short8*)&Wl[base + sh * 8] = pack8(h0, h1);
        }
    }

    float bsum[4];
    {
        int j = j0 + (tid & 15);
#pragma unroll
        for (int g = 0; g < 4; ++g) bsum[g] = b_ih[g * HH + j] + b_hh[g * HH + j];
    }
    float creg[4] = {0.f, 0.f, 0.f, 0.f};
    __syncthreads();

    const size_t HS = (size_t)NROWS * HH;
    for (int t = 0; t < TT; ++t) {
        const int p  = t & 1;
        const int te = dirb ? (TT - 1 - t) : t;
        const bf16* hb = h_hi + (size_t)p * HS;
        const bf16* lb = h_lo + (size_t)p * HS;
        const bf16* xr0 = x_bf + ((size_t)(s * TT + te) * TB) * EMB;

        f32x4 acc[4];
#pragma unroll
        for (int mt = 0; mt < 4; ++mt) acc[mt] = (f32x4)0.f;

        const bf16 *ph[4], *pl[4], *px[4];
#pragma unroll
        for (int mt = 0; mt < 4; ++mt) {
            int r = r0 + mt * 16 + l16;
            ph[mt] = hb + (size_t)r * HH;
            pl[mt] = lb + (size_t)r * HH;
            px[mt] = xr0 + (size_t)(r & 127) * EMB;
        }

        for (int kk = 0; kk < 16; ++kk) {
            int cbse = ((w * 16 + kk) * 16 + l16) * 64;
            short8 fx = *(const short8*)&Wl[cbse + ((kq ^ (lane & 7)) * 8)];
            short8 fh = *(const short8*)&Wl[cbse + (((kq + 4) ^ (lane & 7)) * 8)];
            int k0 = kk * 32 + kq * 8;
#pragma unroll
            for (int mt = 0; mt < 4; ++mt) {
                short8 ax  = *(const short8*)(px[mt] + k0);
                short8 ahi = *(const short8*)(ph[mt] + k0);
                short8 alo = *(const short8*)(pl[mt] + k0);
                acc[mt] = __builtin_amdgcn_mfma_f32_16x16x32_bf16(ax,  fx, acc[mt], 0, 0, 0);
                acc[mt] = __builtin_amdgcn_mfma_f32_16x16x32_bf16(alo, fh, acc[mt], 0, 0, 0);
                acc[mt] = __builtin_amdgcn_mfma_f32_16x16x32_bf16(ahi, fh, acc[mt], 0, 0, 0);
            }
        }
#pragma unroll
        for (int mt = 0; mt < 4; ++mt)
#pragma unroll
            for (int q = 0; q < 4; ++q)
                ga[w][mt * 16 + kq * 4 + q][l16] = acc[mt][q];
        __syncthreads();

        bf16* hob = h_hi + (size_t)(p ^ 1) * HS;
        bf16* lob = h_lo + (size_t)(p ^ 1) * HS;
        const int colc = tid & 15;
        const int j = j0 + colc;
#pragma unroll
        for (int q = 0; q < 4; ++q) {
            int rl = (tid >> 4) + q * 16;
            int r  = r0 + rl;
            float pi = ga[0][rl][colc] + bsum[0];
            float pf = ga[1][rl][colc] + bsum[1];
            float pg = ga[2][rl][colc] + bsum[2];
            float po = ga[3][rl][colc] + bsum[3];
            float si = 1.f / (1.f + expf(-pi));
            float sf = 1.f / (1.f + expf(-pf));
            float so = 1.f / (1.f + expf(-po));
            float tg = tanhf(pg);
            float cn = sf * creg[q] + si * tg;
            float hn = so * tanhf(cn);
            creg[q] = cn;
            size_t idx = (size_t)r * HH + j;
            bf16 hi = f2bf(hn);
            hob[idx] = hi;
            lob[idx] = f2bf(hn - bf2f(hi));
            if (t == TT - 1) h_fin[idx] = hn;
        }
        if (t == TT - 1) break;

        __syncthreads();
        if (tid == 0)
            __hip_atomic_store(&slots[mi * 32 + cj], t + 1,
                               __ATOMIC_RELEASE, __HIP_MEMORY_SCOPE_AGENT);
        if (tid < 64) {
            const int tgt = t + 1;
            while (true) {
                int v = (lane < 32)
                    ? __hip_atomic_load(&slots[mi * 32 + lane],
                                        __ATOMIC_RELAXED, __HIP_MEMORY_SCOPE_AGENT)
                    : tgt;
                if (__all(v >= tgt)) break;
                __builtin_amdgcn_s_sleep(1);
            }
            __builtin_amdgcn_fence(__ATOMIC_ACQUIRE, "agent");
        }
        __syncthreads();
    }
}

// ---------------------------------------------------------------------------
// FALLBACK-2: per-step kernel (round-3), x gathered from embed
// ---------------------------------------------------------------------------
template<int GATH>
__global__ __launch_bounds__(256) void k_step(
    const bf16* __restrict__ x_bf, const float* __restrict__ embed,
    const int* __restrict__ tok_h, const int* __restrict__ tok_p,
    const bf16* __restrict__ W_ihb, const bf16* __restrict__ W_hhb,
    const float* __restrict__ b_ih, const float* __restrict__ b_hh,
    const bf16* __restrict__ h_hi_in, const bf16* __restrict__ h_lo_in,
    bf16* __restrict__ h_hi_out, bf16* __restrict__ h_lo_out,
    float* __restrict__ c_buf, float* __restrict__ h_fin, int t)
{
    __shared__ float lds[4][64][17];

    const int blk = blockIdx.x;
    const int mi = blk >> 5;
    const int ji = blk & 31;
    const int w    = threadIdx.x >> 6;
    const int lane = threadIdx.x & 63;
    const int l16 = lane & 15;
    const int kq  = lane >> 4;

    const int run = mi >> 1;
    const int s   = run >> 1;
    const int te  = (run & 1) ? (TT - 1 - t) : t;
    const int r0  = mi * 64;

    const bf16*  hhp[4];
    const bf16*  hlp[4];
    const bf16*  xbp[4];
    const float* xfp[4];
#pragma unroll
    for (int mt = 0; mt < 4; ++mt) {
        int r = r0 + mt * 16 + l16;
        hhp[mt] = h_hi_in + (size_t)r * HH;
        hlp[mt] = h_lo_in + (size_t)r * HH;
        int b = r & 127;
        if (GATH) {
            xbp[mt] = x_bf + (((size_t)s * TT + te) * TB + b) * EMB;
        } else {
            int tok = (s ? tok_p : tok_h)[b * TT + te];
            xfp[mt] = embed + (size_t)tok * EMB;
        }
    }

    const int gcol = w * HH + ji * 16 + l16;
    const bf16* wh = W_hhb + (size_t)gcol * HH;
    const bf16* wx = W_ihb + (size_t)gcol * EMB;

    f32x4 acc[4];
#pragma unroll
    for (int mt = 0; mt < 4; ++mt) acc[mt] = (f32x4)0.f;

    for (int kk = 0; kk < HH / 32; ++kk) {
        const int k0 = kk * 32 + kq * 8;
        short8 bwh = *reinterpret_cast<const short8*>(wh + k0);
        short8 bwx = *reinterpret_cast<const short8*>(wx + k0);
#pragma unroll
        for (int mt = 0; mt < 4; ++mt) {
            short8 ax;
            if (GATH) {
                ax = *reinterpret_cast<const short8*>(xbp[mt] + k0);
            } else {
                float4 v0 = *reinterpret_cast<const float4*>(xfp[mt] + k0);
                float4 v1 = *reinterpret_cast<const float4*>(xfp[mt] + k0 + 4);
                ax = pack8(v0, v1);
            }
            short8 ahi = *reinterpret_cast<const short8*>(hhp[mt] + k0);
            short8 alo = *reinterpret_cast<const short8*>(hlp[mt] + k0);
            acc[mt] = __builtin_amdgcn_mfma_f32_16x16x32_bf16(ax,  bwx, acc[mt], 0, 0, 0);
            acc[mt] = __builtin_amdgcn_mfma_f32_16x16x32_bf16(alo, bwh, acc[mt], 0, 0, 0);
            acc[mt] = __builtin_amdgcn_mfma_f32_16x16x32_bf16(ahi, bwh, acc[mt], 0, 0, 0);
        }
    }
#pragma unroll
    for (int mt = 0; mt < 4; ++mt)
#pragma unroll
        for (int q = 0; q < 4; ++q)
            lds[w][mt * 16 + kq * 4 + q][l16] = acc[mt][q];
    __syncthreads();

    const int tid = threadIdx.x;
#pragma unroll
    for (int q = 0; q < 4; ++q) {
        int cell = tid + q * 256;
        int rl  = cell >> 4;
        int col = cell & 15;
        int r = r0 + rl;
        int j = ji * 16 + col;

        float pi = lds[0][rl][col] + b_ih[j]          + b_hh[j];
        float pf = lds[1][rl][col] + b_ih[HH + j]     + b_hh[HH + j];
        float pg = lds[2][rl][col] + b_ih[2 * HH + j] + b_hh[2 * HH + j];
        float po = lds[3][rl][col] + b_ih[3 * HH + j] + b_hh[3 * HH + j];

        float si = 1.f / (1.f + expf(-pi));
        float sf = 1.f / (1.f + expf(-pf));
        float so = 1.f / (1.f + expf(-po));
        float tg = tanhf(pg);

        size_t idx = (size_t)r * HH + j;
        float cn = sf * c_buf[idx] + si * tg;
        float hn = so * tanhf(cn);
        c_buf[idx] = cn;

        bf16 hi = f2bf(hn);
        h_hi_out[idx] = hi;
        h_lo_out[idx] = f2bf(hn - bf2f(hi));
        if (t == TT - 1) h_fin[idx] = hn;
    }
}

// ---------------------------------------------------------------------------
// features [hyp, prem, prem-hyp, hyp*prem] + LayerNorm(4096); block per row
// ---------------------------------------------------------------------------
__global__ __launch_bounds__(256) void k_feat_ln0(
    const float* __restrict__ h_fin, const float* __restrict__ g,
    const float* __restrict__ be, bf16* __restrict__ f_out)
{
    const int b = blockIdx.x;
    const int tid = threadIdx.x;
    float v[16];
    float s = 0.f, sq = 0.f;
#pragma unroll
    for (int i = 0; i < 16; ++i) {
        int e = i * 256 + tid;
        int region = e >> 10;
        int idx = e & 1023;
        int runh = (idx < 512) ? 0 : 1;
        int jj = idx & 511;
        float hy = h_fin[((size_t)(runh * TB + b)) * HH + jj];
        float pr = h_fin[((size_t)((runh + 2) * TB + b)) * HH + jj];
        float val = (region == 0) ? hy : (region == 1) ? pr
                  : (region == 2) ? (pr - hy) : (hy * pr);
        v[i] = val;
        s += val;
        sq += val * val;
    }
    __shared__ float shs[4], shq[4];
    for (int o = 32; o; o >>= 1) { s += __shfl_down(s, o); sq += __shfl_down(sq, o); }
    int w = tid >> 6, lane = tid & 63;
    if (!lane) { shs[w] = s; shq[w] = sq; }
    __syncthreads();
    s  = shs[0] + shs[1] + shs[2] + shs[3];
    sq = shq[0] + shq[1] + shq[2] + shq[3];
    float mean = s / (float)F4;
    float var  = sq / (float)F4 - mean * mean;
    float rstd = rsqrtf(var + 1e-6f);
#pragma unroll
    for (int i = 0; i < 16; ++i) {
        int e = i * 256 + tid;
        float nv = (v[i] - mean) * rstd * g[e] + be[e];
        f_out[(size_t)b * F4 + e] = f2bf(nv);
    }
}

// ---------------------------------------------------------------------------
// split-K MLP partial GEMM + reduce
// ---------------------------------------------------------------------------
template<int KTOT, int NCH>
__global__ __launch_bounds__(256) void k_mlp_sk(
    const bf16* __restrict__ A, const float* __restrict__ Bw,
    float* __restrict__ part)
{
    const int KC = KTOT / NCH;
    const int nb = blockIdx.x, mb = blockIdx.y, kc = blockIdx.z;
    const int w    = threadIdx.x >> 6;
    const int lane = threadIdx.x & 63;
    const int wr = w >> 1, wc = w & 1;
    const int l16 = lane & 15;
    const int kq  = lane >> 4;
    const int m0 = mb * 64 + wr * 32;
    const int c0 = nb * 64 + wc * 32;

    f32x4 acc[2][2];
#pragma unroll
    for (int i = 0; i < 2; ++i)
#pragma unroll
        for (int j = 0; j < 2; ++j) acc[i][j] = (f32x4)0.f;

    for (int kk = kc * (KC / 32); kk < (kc + 1) * (KC / 32); ++kk) {
        const int k0 = kk * 32 + kq * 8;
        short8 a[2], bb[2];
#pragma unroll
        for (int i = 0; i < 2; ++i)
            a[i] = *reinterpret_cast<const short8*>(A + (size_t)(m0 + i * 16 + l16) * KTOT + k0);
#pragma unroll
        for (int j = 0; j < 2; ++j) {
            const float* bp = Bw + (size_t)(c0 + j * 16 + l16) * KTOT + k0;
            float4 v0 = *reinterpret_cast<const float4*>(bp);
            float4 v1 = *reinterpret_cast<const float4*>(bp + 4);
            bb[j] = pack8(v0, v1);
        }
#pragma unroll
        for (int i = 0; i < 2; ++i)
#pragma unroll
            for (int j = 0; j < 2; ++j)
                acc[i][j] = __builtin_amdgcn_mfma_f32_16x16x32_bf16(a[i], bb[j], acc[i][j], 0, 0, 0);
    }
#pragma unroll
    for (int i = 0; i < 2; ++i)
#pragma unroll
        for (int j = 0; j < 2; ++j) {
            int gg = c0 + j * 16 + l16;
#pragma unroll
            for (int q = 0; q < 4; ++q) {
                int m = m0 + i * 16 + kq * 4 + q;
                part[((size_t)kc * TB + m) * HD + gg] = acc[i][j][q];
            }
        }
}

template<int NCH>
__global__ __launch_bounds__(256) void k_red(
    const float* __restrict__ part, const float* __restrict__ bias,
    float* __restrict__ act)
{
    int i = blockIdx.x * 256 + threadIdx.x;
    if (i < TB * HD) {
        float s = bias[i & (HD - 1)];
#pragma unroll
        for (int c = 0; c < NCH; ++c) s += part[(size_t)c * TB * HD + i];
        act[i] = fmaxf(s, 0.f);
    }
}

// ---------------------------------------------------------------------------
// LayerNorm over 1024 (f32 in, bf16 out)
// ---------------------------------------------------------------------------
__global__ __launch_bounds__(256) void k_ln(
    const float* __restrict__ x, const float* __restrict__ g,
    const float* __restrict__ be, bf16* __restrict__ out)
{
    const int b = blockIdx.x;
    const int tid = threadIdx.x;
    float v[4];
    float s = 0.f, sq = 0.f;
#pragma unroll
    for (int i = 0; i < 4; ++i) {
        int e = i * 256 + tid;
        float val = x[(size_t)b * HD + e];
        v[i] = val; s += val; sq += val * val;
    }
    __shared__ float shs[4], shq[4];
    for (int o = 32; o; o >>= 1) { s += __shfl_down(s, o); sq += __shfl_down(sq, o); }
    int w = tid >> 6, lane = tid & 63;
    if (!lane) { shs[w] = s; shq[w] = sq; }
    __syncthreads();
    s  = shs[0] + shs[1] + shs[2] + shs[3];
    sq = shq[0] + shq[1] + shq[2] + shq[3];
    float mean = s / (float)HD;
    float var  = sq / (float)HD - mean * mean;
    float rstd = rsqrtf(var + 1e-6f);
#pragma unroll
    for (int i = 0; i < 4; ++i) {
        int e = i * 256 + tid;
        float nv = (v[i] - mean) * rstd * g[e] + be[e];
        out[(size_t)b * HD + e] = f2bf(nv);
    }
}

// ---------------------------------------------------------------------------
// output projection [128,3]
// ---------------------------------------------------------------------------
__global__ __launch_bounds__(256) void k_out(
    const bf16* __restrict__ x, const float* __restrict__ Wt,
    const float* __restrict__ bias, float* __restrict__ out)
{
    const int b = blockIdx.x;
    const int tid = threadIdx.x;
    float p0 = 0.f, p1 = 0.f, p2 = 0.f;
    for (int k = tid; k < HD; k += 256) {
        float xv = bf2f(x[(size_t)b * HD + k]);
        p0 += xv * Wt[k];
        p1 += xv * Wt[HD + k];
        p2 += xv * Wt[2 * HD + k];
    }
    for (int o = 32; o; o >>= 1) {
        p0 += __shfl_down(p0, o);
        p1 += __shfl_down(p1, o);
        p2 += __shfl_down(p2, o);
    }
    __shared__ float sh[4][3];
    int w = tid >> 6, lane = tid & 63;
    if (!lane) { sh[w][0] = p0; sh[w][1] = p1; sh[w][2] = p2; }
    __syncthreads();
    if (tid < 3) {
        out[b * 3 + tid] = sh[0][tid] + sh[1][tid] + sh[2][tid] + sh[3][tid] + bias[tid];
    }
}

// ---------------------------------------------------------------------------
extern "C" void kernel_launch(void* const* d_in, const int* in_sizes, int n_in,
                              void* d_out, int out_size, void* d_ws, size_t ws_size,
                              hipStream_t stream)
{
    const int*   tok_h  = (const int*)  d_in[0];
    const int*   tok_p  = (const int*)  d_in[1];
    const float* embed  = (const float*)d_in[2];
    const float* W_ih   = (const float*)d_in[3];
    const float* W_hh   = (const float*)d_in[4];
    const float* b_ih   = (const float*)d_in[5];
    const float* b_hh   = (const float*)d_in[6];
    const float* mlp1_W = (const float*)d_in[7];
    const float* mlp1_b = (const float*)d_in[8];
    const float* mlp2_W = (const float*)d_in[9];
    const float* mlp2_b = (const float*)d_in[10];
    const float* out_W  = (const float*)d_in[11];
    const float* out_b  = (const float*)d_in[12];
    const float* ln0_g  = (const float*)d_in[13];
    const float* ln0_b  = (const float*)d_in[14];
    const float* ln1_g  = (const float*)d_in[15];
    const float* ln1_b  = (const float*)d_in[16];
    const float* ln2_g  = (const float*)d_in[17];
    const float* ln2_b  = (const float*)d_in[18];

    char* ws = (char*)d_ws;
    size_t off = 0;
    bf16*  f_ln0 = (bf16*)(ws + off);  off += (size_t)TB * F4 * 2;            // 1 MB
    float* part  = (float*)(ws + off); off += (size_t)8 * TB * HD * 4;        // 4 MB
    float* act1  = (float*)(ws + off); off += (size_t)TB * HD * 4;
    bf16*  f_ln1 = (bf16*)(ws + off);  off += (size_t)TB * HD * 2;
    float* act2  = (float*)(ws + off); off += (size_t)TB * HD * 4;
    bf16*  f_ln2 = (bf16*)(ws + off);  off += (size_t)TB * HD * 2;
    float* h_fin = (float*)(ws + off); off += (size_t)NROWS * HH * 4;         // 1 MB
    bf16*  h_hi  = (bf16*)(ws + off);  off += (size_t)2 * NROWS * HH * 2;     // 1 MB
    bf16*  h_lo  = (bf16*)(ws + off);  off += (size_t)2 * NROWS * HH * 2;     // 1 MB
    int*   slots = (int*)(ws + off);   off += 4096;
    float* c_buf = (float*)(ws + off); off += (size_t)NROWS * HH * 4;         // 1 MB
    bf16*  W_ihb = (bf16*)(ws + off);  off += (size_t)G4 * EMB * 2;           // 2 MB
    bf16*  W_hhb = (bf16*)(ws + off);  off += (size_t)G4 * HH * 2;            // 2 MB
    // h_f32 (primary): 2 parities x 512 x 512 f32 = 2 MB, aliases h_hi+h_lo
    float* h_f32 = (float*)h_hi;
    // big region: UNION of xg (primary, 128 MB) and x_bf (fallbacks, 32 MB)
    bf16*  xg   = (bf16*)(ws + off);
    bf16*  x_bf = (bf16*)(ws + off);
    const size_t need_primary = off + (size_t)2 * TT * TB * G4 * 2;   // +128 MB
    const size_t need_f1      = off + (size_t)2 * TT * TB * EMB * 2;  // +32 MB

    // zero h region (2 MB) + slots (contiguous)
    (void)hipMemsetAsync(h_hi, 0, (size_t)4 * NROWS * HH * 2 + 4096, stream);

    const size_t HS = (size_t)NROWS * HH;
    if (ws_size >= need_primary) {
        k_cvt<<<512, 256, 0, stream>>>(W_ih, W_ihb, G4 * EMB / 4);
        k_xproj2<<<dim3(512, 8), 256, 0, stream>>>(tok_h, tok_p, embed, W_ihb,
                                                   b_ih, b_hh, xg);
        k_persist3<<<256, 512, 0, stream>>>(xg, W_hh, b_ih, b_hh,
                                            h_f32, h_fin, slots);
    } else if (ws_size >= need_f1) {
        k_gather<<<4096, 256, 0, stream>>>(tok_h, tok_p, embed, x_bf);
        void* args[] = {(void*)&x_bf, (void*)&W_ih, (void*)&W_hh,
                        (void*)&b_ih, (void*)&b_hh,
                        (void*)&h_hi, (void*)&h_lo, (void*)&h_fin, (void*)&slots};
        (void)hipLaunchCooperativeKernel((void*)k_persist, dim3(256), dim3(256),
                                         args, 0, stream);
    } else {
        (void)hipMemsetAsync(c_buf, 0, (size_t)NROWS * HH * 4, stream);
        k_cvt<<<512, 256, 0, stream>>>(W_ih, W_ihb, G4 * EMB / 4);
        k_cvt<<<512, 256, 0, stream>>>(W_hh, W_hhb, G4 * HH / 4);
        for (int t = 0; t < TT; ++t) {
            int p = t & 1;
            k_step<0><<<256, 256, 0, stream>>>(x_bf, embed, tok_h, tok_p,
                W_ihb, W_hhb, b_ih, b_hh,
                h_hi + (size_t)p * HS, h_lo + (size_t)p * HS,
                h_hi + (size_t)(p ^ 1) * HS, h_lo + (size_t)(p ^ 1) * HS,
                c_buf, h_fin, t);
        }
    }

    // head
    k_feat_ln0<<<TB, 256, 0, stream>>>(h_fin, ln0_g, ln0_b, f_ln0);
    k_mlp_sk<F4, 8><<<dim3(16, 2, 8), 256, 0, stream>>>(f_ln0, mlp1_W, part);
    k_red<8><<<512, 256, 0, stream>>>(part, mlp1_b, act1);
    k_ln<<<TB, 256, 0, stream>>>(act1, ln1_g, ln1_b, f_ln1);
    k_mlp_sk<HD, 4><<<dim3(16, 2, 4), 256, 0, stream>>>(f_ln1, mlp2_W, part);
    k_red<4><<<512, 256, 0, stream>>>(part, mlp2_b, act2);
    k_ln<<<TB, 256, 0, stream>>>(act2, ln2_g, ln2_b, f_ln2);
    k_out<<<TB, 256, 0, stream>>>(f_ln2, out_W, out_b, (float*)d_out);
}